// Round 2
// baseline (2006.819 us; speedup 1.0000x reference)
//
#include <hip/hip_runtime.h>
#include <cstdint>

// Problem constants
#define Bc  2
#define Sc  2048
#define Dc  1024
#define Ec  1024
#define Hc  16
#define HDc 64
#define TTc (Bc*Sc)        // 4096 tokens
#define TILE_R 128
#define NTILES 36          // max padded row tiles: 32 + 4 segments
#define EPSc 1e-5f

// workspace layout (float offsets)
#define WS_Q    0          // [B,H,S,HD] 4194304  (o_pre aliases this after attention)
#define WS_K    4194304
#define WS_V    8388608
#define WS_CTX  12582912   // [B,S,E]
#define WS_MST  16777216   // [B*H*S]
#define WS_LST  16842752
#define WS_PERM 16908288   // int region: perm[NTILES*128] + tmeta[64]

static __device__ __forceinline__ float4 ld4(const float* p){ return *(const float4*)p; }

// ---------------------------------------------------------------------------
// 1. Build modality-sorted token permutation, 128-padded segments per (b,m)
// ---------------------------------------------------------------------------
__global__ void k_perm(const int* __restrict__ mod, int* __restrict__ perm,
                       int* __restrict__ tmeta)
{
    __shared__ int cnt[4], segstart[4];
    int t = threadIdx.x;
    if (t < 4) cnt[t] = 0;
    __syncthreads();
    for (int i = t; i < TTc; i += 256){
        int b = i >> 11; int m = mod[i];
        atomicAdd(&cnt[b*2+m], 1);
    }
    __syncthreads();
    if (t == 0){
        int off = 0;
        for (int i = 0; i < 4; i++){
            segstart[i] = off;
            int pad = ((cnt[i] + TILE_R - 1)/TILE_R)*TILE_R;
            for (int tt = off/TILE_R; tt < (off+pad)/TILE_R; tt++) tmeta[tt] = i;
            off += pad;
        }
        for (int tt = off/TILE_R; tt < NTILES; tt++) tmeta[tt] = -1;
    }
    __syncthreads();
    if (t < 4) cnt[t] = 0;
    for (int i = t; i < NTILES*TILE_R; i += 256) perm[i] = -1;
    __syncthreads();
    for (int i = t; i < TTc; i += 256){
        int b = i >> 11, s = i & 2047; int m = mod[i];
        int r = atomicAdd(&cnt[b*2+m], 1);
        perm[segstart[b*2+m] + r] = s;
    }
}

// ---------------------------------------------------------------------------
// 2. QKV projection: gathered-row GEMM, modality-uniform tiles.
//    tile 128 rows x 128 cols, K-step 16, microtile 8x8.
//    out layout [B,H,S,HD]; grid (E/128, NTILES, 3)
// ---------------------------------------------------------------------------
__global__ __launch_bounds__(256) void k_qkv(
    const float* __restrict__ x, const float* __restrict__ Wq,
    const float* __restrict__ Wk, const float* __restrict__ Wv,
    const int* __restrict__ perm, const int* __restrict__ tmeta,
    float* __restrict__ q, float* __restrict__ k, float* __restrict__ v)
{
    int meta = tmeta[blockIdx.y];
    if (meta < 0) return;
    int b = meta >> 1, m = meta & 1;
    const float* W = (blockIdx.z==0 ? Wq : (blockIdx.z==1 ? Wk : Wv)) + (size_t)m*Dc*Ec;
    float* outp    = (blockIdx.z==0 ? q  : (blockIdx.z==1 ? k  : v));
    int c0 = blockIdx.x * 128;
    int t = threadIdx.x;
    int tr = t >> 4, tc = t & 15;

    __shared__ int   sperm[128];
    __shared__ float xs[128][20];     // rows x 16 d (+pad)
    __shared__ float wt[16][132];     // 16 d x 128 cols (+pad)

    if (t < 128) sperm[t] = perm[blockIdx.y*128 + t];
    float acc[8][8];
    #pragma unroll
    for (int i=0;i<8;i++){
        #pragma unroll
        for (int j=0;j<8;j++) acc[i][j]=0.f;
    }
    __syncthreads();

    for (int d0 = 0; d0 < Dc; d0 += 16){
        #pragma unroll
        for (int u = 0; u < 2; u++){
            int f = u*256 + t;
            int row = f >> 2, dq = f & 3;
            int s_ = sperm[row];
            float4 val = make_float4(0.f,0.f,0.f,0.f);
            if (s_ >= 0) val = ld4(&x[((size_t)(b*Sc + s_))*Dc + d0 + dq*4]);
            *(float4*)&xs[row][dq*4] = val;
            int dd = f >> 5, cq = f & 31;
            *(float4*)&wt[dd][cq*4] = ld4(&W[(size_t)(d0+dd)*Ec + c0 + cq*4]);
        }
        __syncthreads();
        #pragma unroll
        for (int dq = 0; dq < 4; dq++){
            float af[8][4];
            #pragma unroll
            for (int i=0;i<8;i++){
                float4 tv = *(const float4*)&xs[tr+16*i][dq*4];
                af[i][0]=tv.x; af[i][1]=tv.y; af[i][2]=tv.z; af[i][3]=tv.w;
            }
            #pragma unroll
            for (int dd = 0; dd < 4; dd++){
                float4 wa = *(const float4*)&wt[dq*4+dd][4*tc];
                float4 wb = *(const float4*)&wt[dq*4+dd][64 + 4*tc];
                #pragma unroll
                for (int i=0;i<8;i++){
                    float a = af[i][dd];
                    acc[i][0] = fmaf(a, wa.x, acc[i][0]);
                    acc[i][1] = fmaf(a, wa.y, acc[i][1]);
                    acc[i][2] = fmaf(a, wa.z, acc[i][2]);
                    acc[i][3] = fmaf(a, wa.w, acc[i][3]);
                    acc[i][4] = fmaf(a, wb.x, acc[i][4]);
                    acc[i][5] = fmaf(a, wb.y, acc[i][5]);
                    acc[i][6] = fmaf(a, wb.z, acc[i][6]);
                    acc[i][7] = fmaf(a, wb.w, acc[i][7]);
                }
            }
        }
        __syncthreads();
    }
    int h0 = c0 >> 6;   // two heads per 128-col tile
    #pragma unroll
    for (int i=0;i<8;i++){
        int s_ = sperm[tr + 16*i];
        if (s_ < 0) continue;
        float4 o1 = make_float4(acc[i][0],acc[i][1],acc[i][2],acc[i][3]);
        float4 o2 = make_float4(acc[i][4],acc[i][5],acc[i][6],acc[i][7]);
        *(float4*)&outp[(((size_t)(b*Hc + h0  ))*Sc + s_)*HDc + 4*tc] = o1;
        *(float4*)&outp[(((size_t)(b*Hc + h0+1))*Sc + s_)*HDc + 4*tc] = o2;
    }
}

// ---------------------------------------------------------------------------
// 3. Per-head RMSNorm on q and k (wave per 64-elem row). 131072 rows total.
// ---------------------------------------------------------------------------
__global__ __launch_bounds__(256) void k_qknorm(
    float* __restrict__ q, float* __restrict__ k,
    const float* __restrict__ qnw, const float* __restrict__ knw,
    const int* __restrict__ mod)
{
    int wid = threadIdx.x >> 6, lane = threadIdx.x & 63;
    int row = blockIdx.x*4 + wid;           // 0..131071
    int isK = row >= 65536;
    int r = row & 65535;                    // (b*16+h)*2048 + s
    float* buf = isK ? k : q;
    const float* wv = isK ? knw : qnw;
    int s = r & 2047;
    int b = r >> 15;
    int m = mod[b*Sc + s];
    float val = buf[(size_t)r*HDc + lane];
    float ss = val*val;
    #pragma unroll
    for (int o = 32; o > 0; o >>= 1) ss += __shfl_xor(ss, o, 64);
    float rms = rsqrtf(ss*(1.f/64.f) + EPSc);
    buf[(size_t)r*HDc + lane] = val * rms * wv[m*HDc + lane];
}

// ---------------------------------------------------------------------------
// 4. Softmax stats: row max m and sum-exp l per (b,h,row).
//    block = (qtile128, h, b); chunk 64 k-cols; microtile 8x4.
// ---------------------------------------------------------------------------
__global__ __launch_bounds__(256) void k_stats(
    const float* __restrict__ q, const float* __restrict__ k,
    const float* __restrict__ mask, float* __restrict__ mst, float* __restrict__ lst)
{
    int qs0 = blockIdx.x*128; int h = blockIdx.y; int b = blockIdx.z;
    int t = threadIdx.x, tr = t>>4, tc = t&15;
    __shared__ float qt[128][68];
    __shared__ float kt[64][68];
    const float* qb = q + ((size_t)(b*Hc+h))*Sc*HDc;
    const float* kb = k + ((size_t)(b*Hc+h))*Sc*HDc;
    #pragma unroll
    for (int u=0; u<8; u++){
        int f = u*256 + t; int row = f >> 4, dq = f & 15;
        *(float4*)&qt[row][dq*4] = ld4(&qb[(size_t)(qs0+row)*HDc + dq*4]);
    }
    float rm[8], rl[8];
    #pragma unroll
    for (int i=0;i<8;i++){ rm[i] = -3.0e38f; rl[i] = 0.f; }

    for (int kc = 0; kc < Sc; kc += 64){
        __syncthreads();
        #pragma unroll
        for (int u=0; u<4; u++){
            int f = u*256 + t; int row = f >> 4, dq = f & 15;
            *(float4*)&kt[row][dq*4] = ld4(&kb[(size_t)(kc+row)*HDc + dq*4]);
        }
        __syncthreads();
        float dot[8][4];
        #pragma unroll
        for (int i=0;i<8;i++){
            #pragma unroll
            for (int j=0;j<4;j++) dot[i][j]=0.f;
        }
        #pragma unroll
        for (int dq=0; dq<16; dq++){
            float af[8][4], kf[4][4];
            #pragma unroll
            for (int i=0;i<8;i++){ float4 tv = *(const float4*)&qt[tr+16*i][dq*4];
                af[i][0]=tv.x;af[i][1]=tv.y;af[i][2]=tv.z;af[i][3]=tv.w; }
            #pragma unroll
            for (int j=0;j<4;j++){ float4 tv = *(const float4*)&kt[tc+16*j][dq*4];
                kf[j][0]=tv.x;kf[j][1]=tv.y;kf[j][2]=tv.z;kf[j][3]=tv.w; }
            #pragma unroll
            for (int i=0;i<8;i++){
                #pragma unroll
                for (int j=0;j<4;j++)
                    dot[i][j] += af[i][0]*kf[j][0] + af[i][1]*kf[j][1]
                               + af[i][2]*kf[j][2] + af[i][3]*kf[j][3];
            }
        }
        #pragma unroll
        for (int i=0;i<8;i++){
            int gr = qs0 + tr + 16*i;
            float sv[4]; float mx = rm[i];
            #pragma unroll
            for (int j=0;j<4;j++){
                sv[j] = dot[i][j]*0.125f + mask[(size_t)gr*Sc + kc + tc + 16*j];
                mx = fmaxf(mx, sv[j]);
            }
            float a2 = rl[i]*__expf(rm[i]-mx);
            #pragma unroll
            for (int j=0;j<4;j++) a2 += __expf(sv[j]-mx);
            rm[i]=mx; rl[i]=a2;
        }
    }
    __syncthreads();
    float* red = &qt[0][0];     // reuse: need 4096 of 8704 floats
    #pragma unroll
    for (int i=0;i<8;i++){
        red[(tr+16*i)*16 + tc]        = rm[i];
        red[2048 + (tr+16*i)*16 + tc] = rl[i];
    }
    __syncthreads();
    if (t < 128){
        float M = -3.0e38f;
        for (int j=0;j<16;j++) M = fmaxf(M, red[t*16+j]);
        float L = 0.f;
        for (int j=0;j<16;j++) L += red[2048+t*16+j]*__expf(red[t*16+j]-M);
        mst[((size_t)(b*Hc+h))*Sc + qs0 + t] = M;
        lst[((size_t)(b*Hc+h))*Sc + qs0 + t] = L;
    }
}

// ---------------------------------------------------------------------------
// 5. attn_weights output: block owns (b, qtile128, ktile64), loops h,
//    accumulates sum_h p/H in registers, single coalesced store.
// ---------------------------------------------------------------------------
__global__ __launch_bounds__(256) void k_attnw(
    const float* __restrict__ q, const float* __restrict__ k,
    const float* __restrict__ mask, const float* __restrict__ mst,
    const float* __restrict__ lst, float* __restrict__ awout)
{
    int qs0 = blockIdx.x*128, ks0 = blockIdx.y*64, b = blockIdx.z;
    int t = threadIdx.x, tr = t>>4, tc = t&15;
    __shared__ float qt[128][68];
    __shared__ float kt[64][68];
    __shared__ float sm[128], sli[128];
    float aw[8][4];
    #pragma unroll
    for (int i=0;i<8;i++){
        #pragma unroll
        for (int j=0;j<4;j++) aw[i][j]=0.f;
    }

    for (int h=0; h<Hc; h++){
        __syncthreads();
        const float* qb = q + ((size_t)(b*Hc+h))*Sc*HDc;
        const float* kb = k + ((size_t)(b*Hc+h))*Sc*HDc;
        #pragma unroll
        for (int u=0; u<8; u++){
            int f = u*256+t; int row=f>>4, dq=f&15;
            *(float4*)&qt[row][dq*4] = ld4(&qb[(size_t)(qs0+row)*HDc + dq*4]);
        }
        #pragma unroll
        for (int u=0; u<4; u++){
            int f = u*256+t; int row=f>>4, dq=f&15;
            *(float4*)&kt[row][dq*4] = ld4(&kb[(size_t)(ks0+row)*HDc + dq*4]);
        }
        if (t < 128){
            sm[t]  = mst[((size_t)(b*Hc+h))*Sc + qs0 + t];
            sli[t] = 1.f / lst[((size_t)(b*Hc+h))*Sc + qs0 + t];
        }
        __syncthreads();
        float dot[8][4];
        #pragma unroll
        for (int i=0;i<8;i++){
            #pragma unroll
            for (int j=0;j<4;j++) dot[i][j]=0.f;
        }
        #pragma unroll
        for (int dq=0; dq<16; dq++){
            float af[8][4], kf[4][4];
            #pragma unroll
            for (int i=0;i<8;i++){ float4 tv = *(const float4*)&qt[tr+16*i][dq*4];
                af[i][0]=tv.x;af[i][1]=tv.y;af[i][2]=tv.z;af[i][3]=tv.w; }
            #pragma unroll
            for (int j=0;j<4;j++){ float4 tv = *(const float4*)&kt[tc+16*j][dq*4];
                kf[j][0]=tv.x;kf[j][1]=tv.y;kf[j][2]=tv.z;kf[j][3]=tv.w; }
            #pragma unroll
            for (int i=0;i<8;i++){
                #pragma unroll
                for (int j=0;j<4;j++)
                    dot[i][j] += af[i][0]*kf[j][0] + af[i][1]*kf[j][1]
                               + af[i][2]*kf[j][2] + af[i][3]*kf[j][3];
            }
        }
        #pragma unroll
        for (int i=0;i<8;i++){
            int r = tr+16*i; int gr = qs0 + r;
            float mm = sm[r], li = sli[r];
            #pragma unroll
            for (int j=0;j<4;j++){
                float s = dot[i][j]*0.125f + mask[(size_t)gr*Sc + ks0 + tc + 16*j];
                aw[i][j] += __expf(s - mm)*li;
            }
        }
    }
    #pragma unroll
    for (int i=0;i<8;i++){
        #pragma unroll
        for (int j=0;j<4;j++)
            awout[(size_t)b*Sc*Sc + (size_t)(qs0+tr+16*i)*Sc + ks0 + tc + 16*j]
                = aw[i][j]*(1.f/16.f);
    }
}

// ---------------------------------------------------------------------------
// 6. Flash-style PV with precomputed stats: block (qtile128, h, b).
//    p staged in LDS aliased over the K tile (two row-halves); V staged bf16.
// ---------------------------------------------------------------------------
__global__ __launch_bounds__(256) void k_flash(
    const float* __restrict__ q, const float* __restrict__ k,
    const float* __restrict__ v, const float* __restrict__ mask,
    const float* __restrict__ mst, const float* __restrict__ lst,
    float* __restrict__ ctx)
{
    int qs0 = blockIdx.x*128; int h = blockIdx.y; int b = blockIdx.z;
    int t = threadIdx.x, tr = t>>4, tc = t&15;
    __shared__ float qt[128][68];
    __shared__ float ktps[64][68];            // K tile during QK, then p stage
    __shared__ unsigned short vt[64][72];     // V tile, bf16
    __shared__ float sm[128], sli[128];
    const float* qb = q + ((size_t)(b*Hc+h))*Sc*HDc;
    const float* kb = k + ((size_t)(b*Hc+h))*Sc*HDc;
    const float* vb = v + ((size_t)(b*Hc+h))*Sc*HDc;
    #pragma unroll
    for (int u=0; u<8; u++){
        int f=u*256+t; int row=f>>4, dq=f&15;
        *(float4*)&qt[row][dq*4] = ld4(&qb[(size_t)(qs0+row)*HDc + dq*4]);
    }
    if (t<128){
        sm[t]  = mst[((size_t)(b*Hc+h))*Sc + qs0 + t];
        sli[t] = 1.f / lst[((size_t)(b*Hc+h))*Sc + qs0 + t];
    }
    float oacc[8][4];
    #pragma unroll
    for (int i=0;i<8;i++){
        #pragma unroll
        for (int j=0;j<4;j++) oacc[i][j]=0.f;
    }

    for (int kc=0; kc<Sc; kc+=64){
        __syncthreads();
        #pragma unroll
        for (int u=0; u<4; u++){
            int f=u*256+t; int row=f>>4, dq=f&15;
            *(float4*)&ktps[row][dq*4] = ld4(&kb[(size_t)(kc+row)*HDc + dq*4]);
            float4 vv = ld4(&vb[(size_t)(kc+row)*HDc + dq*4]);
            ushort4 vs;
            vs.x = (unsigned short)((__float_as_uint(vv.x) + 0x8000u) >> 16);
            vs.y = (unsigned short)((__float_as_uint(vv.y) + 0x8000u) >> 16);
            vs.z = (unsigned short)((__float_as_uint(vv.z) + 0x8000u) >> 16);
            vs.w = (unsigned short)((__float_as_uint(vv.w) + 0x8000u) >> 16);
            *(ushort4*)&vt[row][dq*4] = vs;
        }
        __syncthreads();
        float dot[8][4];
        #pragma unroll
        for (int i=0;i<8;i++){
            #pragma unroll
            for (int j=0;j<4;j++) dot[i][j]=0.f;
        }
        #pragma unroll
        for (int dq=0; dq<16; dq++){
            float af[8][4], kf[4][4];
            #pragma unroll
            for (int i=0;i<8;i++){ float4 tv = *(const float4*)&qt[tr+16*i][dq*4];
                af[i][0]=tv.x;af[i][1]=tv.y;af[i][2]=tv.z;af[i][3]=tv.w; }
            #pragma unroll
            for (int j=0;j<4;j++){ float4 tv = *(const float4*)&ktps[tc+16*j][dq*4];
                kf[j][0]=tv.x;kf[j][1]=tv.y;kf[j][2]=tv.z;kf[j][3]=tv.w; }
            #pragma unroll
            for (int i=0;i<8;i++){
                #pragma unroll
                for (int j=0;j<4;j++)
                    dot[i][j] += af[i][0]*kf[j][0] + af[i][1]*kf[j][1]
                               + af[i][2]*kf[j][2] + af[i][3]*kf[j][3];
            }
        }
        __syncthreads();   // QK done everywhere; ktps reusable as p stage
        // ---- half A: q-rows 0..63 ----
        #pragma unroll
        for (int i=0;i<4;i++){
            int r = tr+16*i; int gr = qs0 + r;
            #pragma unroll
            for (int j=0;j<4;j++){
                float s = dot[i][j]*0.125f + mask[(size_t)gr*Sc + kc + tc + 16*j];
                ktps[r][tc+16*j] = __expf(s - sm[r])*sli[r];
            }
        }
        __syncthreads();
        #pragma unroll
        for (int u2=0; u2<16; u2++){
            float pf[4][4], vf[4][4];
            #pragma unroll
            for (int i=0;i<4;i++){ float4 tv = *(const float4*)&ktps[tr+16*i][u2*4];
                pf[i][0]=tv.x;pf[i][1]=tv.y;pf[i][2]=tv.z;pf[i][3]=tv.w; }
            #pragma unroll
            for (int w=0;w<4;w++){
                ushort4 us = *(const ushort4*)&vt[u2*4+w][4*tc];
                vf[w][0] = __uint_as_float((unsigned)us.x<<16);
                vf[w][1] = __uint_as_float((unsigned)us.y<<16);
                vf[w][2] = __uint_as_float((unsigned)us.z<<16);
                vf[w][3] = __uint_as_float((unsigned)us.w<<16);
            }
            #pragma unroll
            for (int i=0;i<4;i++){
                #pragma unroll
                for (int w=0;w<4;w++){
                    float p = pf[i][w];
                    oacc[i][0] = fmaf(p, vf[w][0], oacc[i][0]);
                    oacc[i][1] = fmaf(p, vf[w][1], oacc[i][1]);
                    oacc[i][2] = fmaf(p, vf[w][2], oacc[i][2]);
                    oacc[i][3] = fmaf(p, vf[w][3], oacc[i][3]);
                }
            }
        }
        __syncthreads();
        // ---- half B: q-rows 64..127 ----
        #pragma unroll
        for (int i=4;i<8;i++){
            int rl_ = tr+16*(i-4); int rt = tr+16*i; int gr = qs0 + rt;
            #pragma unroll
            for (int j=0;j<4;j++){
                float s = dot[i][j]*0.125f + mask[(size_t)gr*Sc + kc + tc + 16*j];
                ktps[rl_][tc+16*j] = __expf(s - sm[rt])*sli[rt];
            }
        }
        __syncthreads();
        #pragma unroll
        for (int u2=0; u2<16; u2++){
            float pf[4][4], vf[4][4];
            #pragma unroll
            for (int i=0;i<4;i++){ float4 tv = *(const float4*)&ktps[tr+16*i][u2*4];
                pf[i][0]=tv.x;pf[i][1]=tv.y;pf[i][2]=tv.z;pf[i][3]=tv.w; }
            #pragma unroll
            for (int w=0;w<4;w++){
                ushort4 us = *(const ushort4*)&vt[u2*4+w][4*tc];
                vf[w][0] = __uint_as_float((unsigned)us.x<<16);
                vf[w][1] = __uint_as_float((unsigned)us.y<<16);
                vf[w][2] = __uint_as_float((unsigned)us.z<<16);
                vf[w][3] = __uint_as_float((unsigned)us.w<<16);
            }
            #pragma unroll
            for (int i=0;i<4;i++){
                #pragma unroll
                for (int w=0;w<4;w++){
                    float p = pf[i][w];
                    oacc[4+i][0] = fmaf(p, vf[w][0], oacc[4+i][0]);
                    oacc[4+i][1] = fmaf(p, vf[w][1], oacc[4+i][1]);
                    oacc[4+i][2] = fmaf(p, vf[w][2], oacc[4+i][2]);
                    oacc[4+i][3] = fmaf(p, vf[w][3], oacc[4+i][3]);
                }
            }
        }
    }
    #pragma unroll
    for (int i=0;i<8;i++){
        float4 o = make_float4(oacc[i][0],oacc[i][1],oacc[i][2],oacc[i][3]);
        *(float4*)&ctx[((size_t)(b*Sc + qs0 + tr+16*i))*Ec + h*HDc + 4*tc] = o;
    }
}

// ---------------------------------------------------------------------------
// 7. Output projection: gathered-row GEMM ctx @ Wo[m] -> o_pre [B,S,D]
// ---------------------------------------------------------------------------
__global__ __launch_bounds__(256) void k_oproj(
    const float* __restrict__ ctx, const float* __restrict__ Wo,
    const int* __restrict__ perm, const int* __restrict__ tmeta,
    float* __restrict__ opre)
{
    int meta = tmeta[blockIdx.y];
    if (meta < 0) return;
    int b = meta >> 1, m = meta & 1;
    const float* W = Wo + (size_t)m*Ec*Dc;
    int c0 = blockIdx.x * 128;
    int t = threadIdx.x;
    int tr = t >> 4, tc = t & 15;
    __shared__ int   sperm[128];
    __shared__ float xs[128][20];
    __shared__ float wt[16][132];
    if (t < 128) sperm[t] = perm[blockIdx.y*128 + t];
    float acc[8][8];
    #pragma unroll
    for (int i=0;i<8;i++){
        #pragma unroll
        for (int j=0;j<8;j++) acc[i][j]=0.f;
    }
    __syncthreads();
    for (int d0 = 0; d0 < Ec; d0 += 16){
        #pragma unroll
        for (int u = 0; u < 2; u++){
            int f = u*256 + t;
            int row = f >> 2, dq = f & 3;
            int s_ = sperm[row];
            float4 val = make_float4(0.f,0.f,0.f,0.f);
            if (s_ >= 0) val = ld4(&ctx[((size_t)(b*Sc + s_))*Ec + d0 + dq*4]);
            *(float4*)&xs[row][dq*4] = val;
            int dd = f >> 5, cq = f & 31;
            *(float4*)&wt[dd][cq*4] = ld4(&W[(size_t)(d0+dd)*Dc + c0 + cq*4]);
        }
        __syncthreads();
        #pragma unroll
        for (int dq = 0; dq < 4; dq++){
            float af[8][4];
            #pragma unroll
            for (int i=0;i<8;i++){
                float4 tv = *(const float4*)&xs[tr+16*i][dq*4];
                af[i][0]=tv.x; af[i][1]=tv.y; af[i][2]=tv.z; af[i][3]=tv.w;
            }
            #pragma unroll
            for (int dd = 0; dd < 4; dd++){
                float4 wa = *(const float4*)&wt[dq*4+dd][4*tc];
                float4 wb = *(const float4*)&wt[dq*4+dd][64 + 4*tc];
                #pragma unroll
                for (int i=0;i<8;i++){
                    float a = af[i][dd];
                    acc[i][0] = fmaf(a, wa.x, acc[i][0]);
                    acc[i][1] = fmaf(a, wa.y, acc[i][1]);
                    acc[i][2] = fmaf(a, wa.z, acc[i][2]);
                    acc[i][3] = fmaf(a, wa.w, acc[i][3]);
                    acc[i][4] = fmaf(a, wb.x, acc[i][4]);
                    acc[i][5] = fmaf(a, wb.y, acc[i][5]);
                    acc[i][6] = fmaf(a, wb.z, acc[i][6]);
                    acc[i][7] = fmaf(a, wb.w, acc[i][7]);
                }
            }
        }
        __syncthreads();
    }
    #pragma unroll
    for (int i=0;i<8;i++){
        int s_ = sperm[tr + 16*i];
        if (s_ < 0) continue;
        float4 o1 = make_float4(acc[i][0],acc[i][1],acc[i][2],acc[i][3]);
        float4 o2 = make_float4(acc[i][4],acc[i][5],acc[i][6],acc[i][7]);
        *(float4*)&opre[((size_t)(b*Sc + s_))*Dc + c0 + 4*tc]      = o1;
        *(float4*)&opre[((size_t)(b*Sc + s_))*Dc + c0 + 64 + 4*tc] = o2;
    }
}

// ---------------------------------------------------------------------------
// 8. Final RMSNorm over D with attn_norm_w[m] -> out
// ---------------------------------------------------------------------------
__global__ __launch_bounds__(256) void k_onorm(
    const float* __restrict__ opre, const float* __restrict__ anw,
    const int* __restrict__ mod, float* __restrict__ out)
{
    int row = blockIdx.x;           // b*S + s
    int m = mod[row];
    int t = threadIdx.x;
    float val[4];
    float ss = 0.f;
    #pragma unroll
    for (int j=0;j<4;j++){
        val[j] = opre[(size_t)row*Dc + t + 256*j];
        ss += val[j]*val[j];
    }
    #pragma unroll
    for (int o=32;o>0;o>>=1) ss += __shfl_xor(ss, o, 64);
    __shared__ float red[4];
    int wid = t>>6, lane = t&63;
    if (lane==0) red[wid]=ss;
    __syncthreads();
    float tot = red[0]+red[1]+red[2]+red[3];
    float rms = rsqrtf(tot*(1.f/1024.f) + EPSc);
    #pragma unroll
    for (int j=0;j<4;j++)
        out[(size_t)row*Dc + t + 256*j] = val[j]*rms*anw[m*Dc + t + 256*j];
}

// ---------------------------------------------------------------------------
extern "C" void kernel_launch(void* const* d_in, const int* in_sizes, int n_in,
                              void* d_out, int out_size, void* d_ws, size_t ws_size,
                              hipStream_t stream)
{
    const float* x    = (const float*)d_in[0];
    const float* mask = (const float*)d_in[1];
    const int*   mod  = (const int*)  d_in[2];
    const float* Wq   = (const float*)d_in[3];
    const float* Wk   = (const float*)d_in[4];
    const float* Wv   = (const float*)d_in[5];
    const float* Wo   = (const float*)d_in[6];
    const float* qnw  = (const float*)d_in[7];
    const float* knw  = (const float*)d_in[8];
    const float* anw  = (const float*)d_in[9];

    float* out   = (float*)d_out;                    // [B,S,D]
    float* awout = out + (size_t)Bc*Sc*Dc;           // [B,S,S]

    float* ws   = (float*)d_ws;
    float* q    = ws + WS_Q;
    float* k    = ws + WS_K;
    float* v    = ws + WS_V;
    float* ctx  = ws + WS_CTX;
    float* mst  = ws + WS_MST;
    float* lst  = ws + WS_LST;
    int*   perm  = (int*)(ws + WS_PERM);
    int*   tmeta = perm + NTILES*TILE_R;
    float* opre = ws + WS_Q;                         // alias q (dead after attention)

    k_perm  <<<dim3(1),           256, 0, stream>>>(mod, perm, tmeta);
    k_qkv   <<<dim3(8,NTILES,3),  256, 0, stream>>>(x, Wq, Wk, Wv, perm, tmeta, q, k, v);
    k_qknorm<<<dim3(32768),       256, 0, stream>>>(q, k, qnw, knw, mod);
    k_stats <<<dim3(16,16,2),     256, 0, stream>>>(q, k, mask, mst, lst);
    k_attnw <<<dim3(16,32,2),     256, 0, stream>>>(q, k, mask, mst, lst, awout);
    k_flash <<<dim3(16,16,2),     256, 0, stream>>>(q, k, v, mask, mst, lst, ctx);
    k_oproj <<<dim3(8,NTILES),    256, 0, stream>>>(ctx, Wo, perm, tmeta, opre);
    k_onorm <<<dim3(4096),        256, 0, stream>>>(opre, anw, mod, out);
}

// Round 3
// 573.913 us; speedup vs baseline: 3.4967x; 3.4967x over previous
//
#include <hip/hip_runtime.h>
#include <cstdint>

#define Bc  2
#define Sc  2048
#define Dc  1024
#define Ec  1024
#define Hc  16
#define HDc 64
#define TTc (Bc*Sc)
#define TILE_R 128
#define NTILES 36
#define EPSc 1e-5f

typedef unsigned short u16;
using bf8   = __attribute__((ext_vector_type(8))) short;
using f32x4 = __attribute__((ext_vector_type(4))) float;
#define MFMA(a,b,c) __builtin_amdgcn_mfma_f32_16x16x32_bf16(a,b,c,0,0,0)

static __device__ __forceinline__ u16 f2b(float f){
    return (u16)((__float_as_uint(f) + 0x8000u) >> 16);
}
static __device__ __forceinline__ float b2f(u16 s){
    return __uint_as_float(((unsigned)s) << 16);
}

// ---------------------------------------------------------------------------
// 1. modality-sorted token permutation, 128-padded segments per (b,m)
// ---------------------------------------------------------------------------
__global__ void k_perm(const int* __restrict__ mod, int* __restrict__ perm,
                       int* __restrict__ tmeta)
{
    __shared__ int cnt[4], segstart[4];
    int t = threadIdx.x;
    if (t < 4) cnt[t] = 0;
    __syncthreads();
    for (int i = t; i < TTc; i += 256){
        int b = i >> 11; int m = mod[i];
        atomicAdd(&cnt[b*2+m], 1);
    }
    __syncthreads();
    if (t == 0){
        int off = 0;
        for (int i = 0; i < 4; i++){
            segstart[i] = off;
            int pad = ((cnt[i] + TILE_R - 1)/TILE_R)*TILE_R;
            for (int tt = off/TILE_R; tt < (off+pad)/TILE_R; tt++) tmeta[tt] = i;
            off += pad;
        }
        for (int tt = off/TILE_R; tt < NTILES; tt++) tmeta[tt] = -1;
    }
    __syncthreads();
    if (t < 4) cnt[t] = 0;
    for (int i = t; i < NTILES*TILE_R; i += 256) perm[i] = -1;
    __syncthreads();
    for (int i = t; i < TTc; i += 256){
        int b = i >> 11, s = i & 2047; int m = mod[i];
        int r = atomicAdd(&cnt[b*2+m], 1);
        perm[segstart[b*2+m] + r] = s;
    }
}

// ---------------------------------------------------------------------------
// 2. fp32 -> bf16 elementwise (x)
// ---------------------------------------------------------------------------
__global__ __launch_bounds__(256) void k_f2b(const float* __restrict__ src,
                                             u16* __restrict__ dst, int n)
{
    int i = (blockIdx.x*256 + threadIdx.x)*4;
    if (i >= n) return;
    float4 v = *(const float4*)&src[i];
    ushort4 o;
    o.x = f2b(v.x); o.y = f2b(v.y); o.z = f2b(v.z); o.w = f2b(v.w);
    *(ushort4*)&dst[i] = o;
}

// ---------------------------------------------------------------------------
// 3. transpose+convert one [2][1024][1024] weight: dst[m][j][i] = src[m][i][j]
// ---------------------------------------------------------------------------
__global__ __launch_bounds__(256) void k_tcvt(const float* __restrict__ src,
                                              u16* __restrict__ dst)
{
    int m = blockIdx.z;
    src += (size_t)m*1048576; dst += (size_t)m*1048576;
    __shared__ float sh[32][33];
    int t = threadIdx.x;
    int i0 = blockIdx.x*32, j0 = blockIdx.y*32;
    {
        int i = t >> 3, j4 = (t & 7)*4;
        *(float4*)&sh[i][j4] = *(const float4*)&src[(size_t)(i0+i)*1024 + j0 + j4];
    }
    __syncthreads();
    {
        int j = t >> 3, i4 = (t & 7)*4;
        ushort4 o;
        o.x = f2b(sh[i4+0][j]); o.y = f2b(sh[i4+1][j]);
        o.z = f2b(sh[i4+2][j]); o.w = f2b(sh[i4+3][j]);
        *(ushort4*)&dst[(size_t)(j0+j)*1024 + i0 + i4] = o;
    }
}

// ---------------------------------------------------------------------------
// 4. QKV projection, MFMA. A = gathered xb rows [128 x 1024], B = wT [e][d].
//    out qb/kb/vb bf16 [B,H,S,HD]. grid (8, NTILES, 3), block 256 (4 waves).
// ---------------------------------------------------------------------------
__global__ __launch_bounds__(256) void k_qkv(
    const u16* __restrict__ xb, const u16* __restrict__ wqT,
    const u16* __restrict__ wkT, const u16* __restrict__ wvT,
    const int* __restrict__ perm, const int* __restrict__ tmeta,
    u16* __restrict__ qb, u16* __restrict__ kb, u16* __restrict__ vb)
{
    int meta = tmeta[blockIdx.y];
    if (meta < 0) return;
    int b = meta >> 1, m = meta & 1;
    const u16* W = (blockIdx.z==0 ? wqT : (blockIdx.z==1 ? wkT : wvT)) + (size_t)m*Ec*Dc;
    u16* outp    = (blockIdx.z==0 ? qb  : (blockIdx.z==1 ? kb  : vb));
    int c0 = blockIdx.x*128;
    int t = threadIdx.x, lane = t & 63, wv_ = t >> 6;
    int quad = lane >> 4, lc = lane & 15;

    __shared__ u16 at[128][72];
    __shared__ u16 bt[128][72];
    __shared__ int sperm[128];
    if (t < 128) sperm[t] = perm[blockIdx.y*128 + t];
    f32x4 acc[2][8];
    #pragma unroll
    for (int i=0;i<2;i++)
        #pragma unroll
        for (int j=0;j<8;j++) acc[i][j] = (f32x4){0.f,0.f,0.f,0.f};
    __syncthreads();

    int rr = t >> 1, hf = t & 1;
    for (int d0 = 0; d0 < Dc; d0 += 64){
        int s_ = sperm[rr];
        if (s_ >= 0){
            const u16* src = xb + ((size_t)(b*Sc + s_))*Dc + d0 + hf*32;
            *(uint4*)&at[rr][hf*32]      = *(const uint4*)(src);
            *(uint4*)&at[rr][hf*32 + 8]  = *(const uint4*)(src + 8);
            *(uint4*)&at[rr][hf*32 + 16] = *(const uint4*)(src + 16);
            *(uint4*)&at[rr][hf*32 + 24] = *(const uint4*)(src + 24);
        } else {
            uint4 z = make_uint4(0,0,0,0);
            *(uint4*)&at[rr][hf*32]      = z;
            *(uint4*)&at[rr][hf*32 + 8]  = z;
            *(uint4*)&at[rr][hf*32 + 16] = z;
            *(uint4*)&at[rr][hf*32 + 24] = z;
        }
        const u16* wsrc = W + (size_t)(c0 + rr)*Dc + d0 + hf*32;
        *(uint4*)&bt[rr][hf*32]      = *(const uint4*)(wsrc);
        *(uint4*)&bt[rr][hf*32 + 8]  = *(const uint4*)(wsrc + 8);
        *(uint4*)&bt[rr][hf*32 + 16] = *(const uint4*)(wsrc + 16);
        *(uint4*)&bt[rr][hf*32 + 24] = *(const uint4*)(wsrc + 24);
        __syncthreads();
        #pragma unroll
        for (int ks = 0; ks < 2; ks++){
            bf8 a0 = *(const bf8*)&at[wv_*32 + lc][ks*32 + quad*8];
            bf8 a1 = *(const bf8*)&at[wv_*32 + 16 + lc][ks*32 + quad*8];
            #pragma unroll
            for (int nb = 0; nb < 8; nb++){
                bf8 bb = *(const bf8*)&bt[nb*16 + lc][ks*32 + quad*8];
                acc[0][nb] = MFMA(a0, bb, acc[0][nb]);
                acc[1][nb] = MFMA(a1, bb, acc[1][nb]);
            }
        }
        __syncthreads();
    }
    int h0 = c0 >> 6;
    #pragma unroll
    for (int mb = 0; mb < 2; mb++){
        #pragma unroll
        for (int r = 0; r < 4; r++){
            int row = wv_*32 + mb*16 + quad*4 + r;
            int s_ = sperm[row];
            if (s_ < 0) continue;
            #pragma unroll
            for (int nb = 0; nb < 8; nb++){
                int col = nb*16 + lc;
                int h = h0 + (col >> 6), hd = col & 63;
                outp[(((size_t)(b*Hc + h))*Sc + s_)*HDc + hd] = f2b(acc[mb][nb][r]);
            }
        }
    }
}

// ---------------------------------------------------------------------------
// 5. per-head RMSNorm on bf16 q and k, in place
// ---------------------------------------------------------------------------
__global__ __launch_bounds__(256) void k_qknorm(
    u16* __restrict__ qb, u16* __restrict__ kb,
    const float* __restrict__ qnw, const float* __restrict__ knw,
    const int* __restrict__ mod)
{
    int wid = threadIdx.x >> 6, lane = threadIdx.x & 63;
    int row = blockIdx.x*4 + wid;
    int isK = row >= 65536;
    int r = row & 65535;
    u16* buf = isK ? kb : qb;
    const float* wv = isK ? knw : qnw;
    int s = r & 2047;
    int b = r >> 15;
    int m = mod[b*Sc + s];
    float val = b2f(buf[(size_t)r*HDc + lane]);
    float ss = val*val;
    #pragma unroll
    for (int o = 32; o > 0; o >>= 1) ss += __shfl_xor(ss, o, 64);
    float rms = rsqrtf(ss*(1.f/64.f) + EPSc);
    buf[(size_t)r*HDc + lane] = f2b(val * rms * wv[m*HDc + lane]);
}

// ---------------------------------------------------------------------------
// 6. V transpose: vb [B,H,S,HD] -> vtb [B,H,HD,S]
// ---------------------------------------------------------------------------
__global__ __launch_bounds__(256) void k_vt(const u16* __restrict__ vb,
                                            u16* __restrict__ vtb)
{
    int idx = blockIdx.x*256 + threadIdx.x;        // over B*H*HD*S
    int s = idx & 2047;
    int rest = idx >> 11;
    int hd = rest & 63;
    int bh = rest >> 6;
    vtb[idx] = vb[((size_t)bh*Sc + s)*HDc + hd];
}

// ---------------------------------------------------------------------------
// 7. softmax stats via MFMA QK^T. grid (16, 16, 2) = (qtile, h, b)
// ---------------------------------------------------------------------------
__global__ __launch_bounds__(256) void k_stats(
    const u16* __restrict__ qb, const u16* __restrict__ kb,
    const float* __restrict__ mask, float* __restrict__ mst, float* __restrict__ lst)
{
    int qs0 = blockIdx.x*128, h = blockIdx.y, b = blockIdx.z;
    int t = threadIdx.x, lane = t & 63, wv_ = t >> 6;
    int quad = lane >> 4, lc = lane & 15;
    __shared__ u16 qt[128][72];
    __shared__ u16 kt[64][72];
    const u16* qp = qb + ((size_t)(b*Hc+h))*Sc*HDc;
    const u16* kp = kb + ((size_t)(b*Hc+h))*Sc*HDc;
    {
        int rr = t >> 1, cc = (t & 1)*32;
        const u16* s = qp + (size_t)(qs0+rr)*HDc + cc;
        *(uint4*)&qt[rr][cc]    = *(const uint4*)(s);
        *(uint4*)&qt[rr][cc+8]  = *(const uint4*)(s+8);
        *(uint4*)&qt[rr][cc+16] = *(const uint4*)(s+16);
        *(uint4*)&qt[rr][cc+24] = *(const uint4*)(s+24);
    }
    float rm[8], rl[8];
    #pragma unroll
    for (int i=0;i<8;i++){ rm[i] = -1.0e30f; rl[i] = 0.f; }

    for (int kc = 0; kc < Sc; kc += 64){
        __syncthreads();
        {
            int rr = t >> 2, cc = (t & 3)*16;
            const u16* s = kp + (size_t)(kc+rr)*HDc + cc;
            *(uint4*)&kt[rr][cc]   = *(const uint4*)(s);
            *(uint4*)&kt[rr][cc+8] = *(const uint4*)(s+8);
        }
        __syncthreads();
        f32x4 acc[2][4];
        #pragma unroll
        for (int i=0;i<2;i++)
            #pragma unroll
            for (int j=0;j<4;j++) acc[i][j] = (f32x4){0.f,0.f,0.f,0.f};
        #pragma unroll
        for (int ks = 0; ks < 2; ks++){
            bf8 a0 = *(const bf8*)&qt[wv_*32 + lc][ks*32 + quad*8];
            bf8 a1 = *(const bf8*)&qt[wv_*32 + 16 + lc][ks*32 + quad*8];
            #pragma unroll
            for (int nb = 0; nb < 4; nb++){
                bf8 bb = *(const bf8*)&kt[nb*16 + lc][ks*32 + quad*8];
                acc[0][nb] = MFMA(a0, bb, acc[0][nb]);
                acc[1][nb] = MFMA(a1, bb, acc[1][nb]);
            }
        }
        #pragma unroll
        for (int mb = 0; mb < 2; mb++){
            #pragma unroll
            for (int r = 0; r < 4; r++){
                int gq = qs0 + wv_*32 + mb*16 + quad*4 + r;
                const float* mrow = &mask[(size_t)gq*Sc + kc + lc];
                float sv[4];
                #pragma unroll
                for (int nb = 0; nb < 4; nb++)
                    sv[nb] = acc[mb][nb][r]*0.125f + mrow[nb*16];
                float mx = fmaxf(fmaxf(sv[0],sv[1]), fmaxf(sv[2],sv[3]));
                int slot = mb*4 + r;
                float nm = fmaxf(rm[slot], mx);
                float a2 = rl[slot]*__expf(rm[slot]-nm);
                #pragma unroll
                for (int nb = 0; nb < 4; nb++) a2 += __expf(sv[nb]-nm);
                rm[slot] = nm; rl[slot] = a2;
            }
        }
    }
    #pragma unroll
    for (int slot = 0; slot < 8; slot++){
        #pragma unroll
        for (int o = 1; o < 16; o <<= 1){
            float m2 = __shfl_xor(rm[slot], o, 64);
            float l2 = __shfl_xor(rl[slot], o, 64);
            float nm = fmaxf(rm[slot], m2);
            rl[slot] = rl[slot]*__expf(rm[slot]-nm) + l2*__expf(m2-nm);
            rm[slot] = nm;
        }
    }
    if (lc == 0){
        #pragma unroll
        for (int mb = 0; mb < 2; mb++){
            #pragma unroll
            for (int r = 0; r < 4; r++){
                int row = qs0 + wv_*32 + mb*16 + quad*4 + r;
                mst[((size_t)(b*Hc+h))*Sc + row] = rm[mb*4+r];
                lst[((size_t)(b*Hc+h))*Sc + row] = rl[mb*4+r];
            }
        }
    }
}

// ---------------------------------------------------------------------------
// 8. attn_weights: grid (qtile16, ktile16, b2); loop h, MFMA QK, accumulate
//    T = sum_h exp(s-m)/l; epilogue multiplies exp(mask)/H.
// ---------------------------------------------------------------------------
__global__ __launch_bounds__(256) void k_attnw(
    const u16* __restrict__ qb, const u16* __restrict__ kb,
    const float* __restrict__ mask, const float* __restrict__ mst,
    const float* __restrict__ lst, float* __restrict__ awout)
{
    int qs0 = blockIdx.x*128, ks0 = blockIdx.y*128, b = blockIdx.z;
    int t = threadIdx.x, lane = t & 63, wv_ = t >> 6;
    int quad = lane >> 4, lc = lane & 15;
    __shared__ u16 qt[128][72];
    __shared__ u16 kt[128][72];
    __shared__ float sm[128], sli[128];
    f32x4 T[2][8];
    #pragma unroll
    for (int i=0;i<2;i++)
        #pragma unroll
        for (int j=0;j<8;j++) T[i][j] = (f32x4){0.f,0.f,0.f,0.f};

    for (int h = 0; h < Hc; h++){
        __syncthreads();
        const u16* qp = qb + ((size_t)(b*Hc+h))*Sc*HDc;
        const u16* kp = kb + ((size_t)(b*Hc+h))*Sc*HDc;
        {
            int rr = t >> 1, cc = (t & 1)*32;
            const u16* s1 = qp + (size_t)(qs0+rr)*HDc + cc;
            *(uint4*)&qt[rr][cc]    = *(const uint4*)(s1);
            *(uint4*)&qt[rr][cc+8]  = *(const uint4*)(s1+8);
            *(uint4*)&qt[rr][cc+16] = *(const uint4*)(s1+16);
            *(uint4*)&qt[rr][cc+24] = *(const uint4*)(s1+24);
            const u16* s2 = kp + (size_t)(ks0+rr)*HDc + cc;
            *(uint4*)&kt[rr][cc]    = *(const uint4*)(s2);
            *(uint4*)&kt[rr][cc+8]  = *(const uint4*)(s2+8);
            *(uint4*)&kt[rr][cc+16] = *(const uint4*)(s2+16);
            *(uint4*)&kt[rr][cc+24] = *(const uint4*)(s2+24);
        }
        if (t < 128){
            sm[t]  = mst[((size_t)(b*Hc+h))*Sc + qs0 + t];
            sli[t] = 1.f / lst[((size_t)(b*Hc+h))*Sc + qs0 + t];
        }
        __syncthreads();
        f32x4 acc[2][8];
        #pragma unroll
        for (int i=0;i<2;i++)
            #pragma unroll
            for (int j=0;j<8;j++) acc[i][j] = (f32x4){0.f,0.f,0.f,0.f};
        #pragma unroll
        for (int ks = 0; ks < 2; ks++){
            bf8 a0 = *(const bf8*)&qt[wv_*32 + lc][ks*32 + quad*8];
            bf8 a1 = *(const bf8*)&qt[wv_*32 + 16 + lc][ks*32 + quad*8];
            #pragma unroll
            for (int nb = 0; nb < 8; nb++){
                bf8 bb = *(const bf8*)&kt[nb*16 + lc][ks*32 + quad*8];
                acc[0][nb] = MFMA(a0, bb, acc[0][nb]);
                acc[1][nb] = MFMA(a1, bb, acc[1][nb]);
            }
        }
        #pragma unroll
        for (int mb = 0; mb < 2; mb++){
            #pragma unroll
            for (int r = 0; r < 4; r++){
                int row = wv_*32 + mb*16 + quad*4 + r;
                float mm = sm[row], li = sli[row];
                #pragma unroll
                for (int nb = 0; nb < 8; nb++){
                    float s = acc[mb][nb][r]*0.125f;
                    T[mb][nb][r] += __expf(fminf(s - mm, 60.f))*li;
                }
            }
        }
    }
    #pragma unroll
    for (int mb = 0; mb < 2; mb++){
        #pragma unroll
        for (int r = 0; r < 4; r++){
            int gq = qs0 + wv_*32 + mb*16 + quad*4 + r;
            #pragma unroll
            for (int nb = 0; nb < 8; nb++){
                int gk = ks0 + nb*16 + lc;
                float mk = mask[(size_t)gq*Sc + gk];
                awout[(size_t)b*Sc*Sc + (size_t)gq*Sc + gk]
                    = T[mb][nb][r]*__expf(mk)*(1.f/16.f);
            }
        }
    }
}

// ---------------------------------------------------------------------------
// 9. flash PV with precomputed stats, MFMA QK + MFMA PV.
//    grid (qtile16, h16, b2). P round-trips LDS in A-layout; V pre-transposed.
// ---------------------------------------------------------------------------
__global__ __launch_bounds__(256) void k_flash(
    const u16* __restrict__ qb, const u16* __restrict__ kb,
    const u16* __restrict__ vtb, const float* __restrict__ mask,
    const float* __restrict__ mst, const float* __restrict__ lst,
    u16* __restrict__ ctxb)
{
    int qs0 = blockIdx.x*128, h = blockIdx.y, b = blockIdx.z;
    int t = threadIdx.x, lane = t & 63, wv_ = t >> 6;
    int quad = lane >> 4, lc = lane & 15;
    __shared__ u16 qt[128][72];
    __shared__ u16 kt[64][72];
    __shared__ u16 vt[64][72];
    __shared__ u16 pt[128][72];
    __shared__ float sm[128], sli[128];
    const u16* qp  = qb  + ((size_t)(b*Hc+h))*Sc*HDc;
    const u16* kp  = kb  + ((size_t)(b*Hc+h))*Sc*HDc;
    const u16* vtp = vtb + ((size_t)(b*Hc+h))*HDc*Sc;
    {
        int rr = t >> 1, cc = (t & 1)*32;
        const u16* s1 = qp + (size_t)(qs0+rr)*HDc + cc;
        *(uint4*)&qt[rr][cc]    = *(const uint4*)(s1);
        *(uint4*)&qt[rr][cc+8]  = *(const uint4*)(s1+8);
        *(uint4*)&qt[rr][cc+16] = *(const uint4*)(s1+16);
        *(uint4*)&qt[rr][cc+24] = *(const uint4*)(s1+24);
    }
    if (t < 128){
        sm[t]  = mst[((size_t)(b*Hc+h))*Sc + qs0 + t];
        sli[t] = 1.f / lst[((size_t)(b*Hc+h))*Sc + qs0 + t];
    }
    f32x4 oacc[2][4];
    #pragma unroll
    for (int i=0;i<2;i++)
        #pragma unroll
        for (int j=0;j<4;j++) oacc[i][j] = (f32x4){0.f,0.f,0.f,0.f};

    for (int kc = 0; kc < Sc; kc += 64){
        __syncthreads();
        {
            int rr = t >> 2, cc = (t & 3)*16;
            const u16* s1 = kp + (size_t)(kc+rr)*HDc + cc;
            *(uint4*)&kt[rr][cc]   = *(const uint4*)(s1);
            *(uint4*)&kt[rr][cc+8] = *(const uint4*)(s1+8);
            const u16* s2 = vtp + (size_t)rr*Sc + kc + cc;
            *(uint4*)&vt[rr][cc]   = *(const uint4*)(s2);
            *(uint4*)&vt[rr][cc+8] = *(const uint4*)(s2+8);
        }
        __syncthreads();
        f32x4 acc[2][4];
        #pragma unroll
        for (int i=0;i<2;i++)
            #pragma unroll
            for (int j=0;j<4;j++) acc[i][j] = (f32x4){0.f,0.f,0.f,0.f};
        #pragma unroll
        for (int ks = 0; ks < 2; ks++){
            bf8 a0 = *(const bf8*)&qt[wv_*32 + lc][ks*32 + quad*8];
            bf8 a1 = *(const bf8*)&qt[wv_*32 + 16 + lc][ks*32 + quad*8];
            #pragma unroll
            for (int nb = 0; nb < 4; nb++){
                bf8 bb = *(const bf8*)&kt[nb*16 + lc][ks*32 + quad*8];
                acc[0][nb] = MFMA(a0, bb, acc[0][nb]);
                acc[1][nb] = MFMA(a1, bb, acc[1][nb]);
            }
        }
        #pragma unroll
        for (int mb = 0; mb < 2; mb++){
            #pragma unroll
            for (int r = 0; r < 4; r++){
                int row = wv_*32 + mb*16 + quad*4 + r;
                int gq = qs0 + row;
                float mm = sm[row], li = sli[row];
                #pragma unroll
                for (int nb = 0; nb < 4; nb++){
                    int gk = kc + nb*16 + lc;
                    float s = acc[mb][nb][r]*0.125f + mask[(size_t)gq*Sc + gk];
                    pt[row][nb*16 + lc] = f2b(__expf(s - mm)*li);
                }
            }
        }
        __syncthreads();
        #pragma unroll
        for (int ks = 0; ks < 2; ks++){
            bf8 a0 = *(const bf8*)&pt[wv_*32 + lc][ks*32 + quad*8];
            bf8 a1 = *(const bf8*)&pt[wv_*32 + 16 + lc][ks*32 + quad*8];
            #pragma unroll
            for (int nb = 0; nb < 4; nb++){
                bf8 bb = *(const bf8*)&vt[nb*16 + lc][ks*32 + quad*8];
                oacc[0][nb] = MFMA(a0, bb, oacc[0][nb]);
                oacc[1][nb] = MFMA(a1, bb, oacc[1][nb]);
            }
        }
    }
    #pragma unroll
    for (int mb = 0; mb < 2; mb++){
        #pragma unroll
        for (int r = 0; r < 4; r++){
            int tok = qs0 + wv_*32 + mb*16 + quad*4 + r;
            #pragma unroll
            for (int nb = 0; nb < 4; nb++){
                int hd = nb*16 + lc;
                ctxb[((size_t)(b*Sc + tok))*Ec + h*HDc + hd] = f2b(oacc[mb][nb][r]);
            }
        }
    }
}

// ---------------------------------------------------------------------------
// 10. output projection, MFMA: A = gathered ctxb rows, B = woT [d][e].
//     out opre fp32 [B,S,D]. grid (8, NTILES).
// ---------------------------------------------------------------------------
__global__ __launch_bounds__(256) void k_oproj(
    const u16* __restrict__ ctxb, const u16* __restrict__ woT,
    const int* __restrict__ perm, const int* __restrict__ tmeta,
    float* __restrict__ opre)
{
    int meta = tmeta[blockIdx.y];
    if (meta < 0) return;
    int b = meta >> 1, m = meta & 1;
    const u16* W = woT + (size_t)m*Ec*Dc;
    int c0 = blockIdx.x*128;
    int t = threadIdx.x, lane = t & 63, wv_ = t >> 6;
    int quad = lane >> 4, lc = lane & 15;
    __shared__ u16 at[128][72];
    __shared__ u16 bt[128][72];
    __shared__ int sperm[128];
    if (t < 128) sperm[t] = perm[blockIdx.y*128 + t];
    f32x4 acc[2][8];
    #pragma unroll
    for (int i=0;i<2;i++)
        #pragma unroll
        for (int j=0;j<8;j++) acc[i][j] = (f32x4){0.f,0.f,0.f,0.f};
    __syncthreads();

    int rr = t >> 1, hf = t & 1;
    for (int d0 = 0; d0 < Ec; d0 += 64){
        int s_ = sperm[rr];
        if (s_ >= 0){
            const u16* src = ctxb + ((size_t)(b*Sc + s_))*Ec + d0 + hf*32;
            *(uint4*)&at[rr][hf*32]      = *(const uint4*)(src);
            *(uint4*)&at[rr][hf*32 + 8]  = *(const uint4*)(src + 8);
            *(uint4*)&at[rr][hf*32 + 16] = *(const uint4*)(src + 16);
            *(uint4*)&at[rr][hf*32 + 24] = *(const uint4*)(src + 24);
        } else {
            uint4 z = make_uint4(0,0,0,0);
            *(uint4*)&at[rr][hf*32]      = z;
            *(uint4*)&at[rr][hf*32 + 8]  = z;
            *(uint4*)&at[rr][hf*32 + 16] = z;
            *(uint4*)&at[rr][hf*32 + 24] = z;
        }
        const u16* wsrc = W + (size_t)(c0 + rr)*Ec + d0 + hf*32;
        *(uint4*)&bt[rr][hf*32]      = *(const uint4*)(wsrc);
        *(uint4*)&bt[rr][hf*32 + 8]  = *(const uint4*)(wsrc + 8);
        *(uint4*)&bt[rr][hf*32 + 16] = *(const uint4*)(wsrc + 16);
        *(uint4*)&bt[rr][hf*32 + 24] = *(const uint4*)(wsrc + 24);
        __syncthreads();
        #pragma unroll
        for (int ks = 0; ks < 2; ks++){
            bf8 a0 = *(const bf8*)&at[wv_*32 + lc][ks*32 + quad*8];
            bf8 a1 = *(const bf8*)&at[wv_*32 + 16 + lc][ks*32 + quad*8];
            #pragma unroll
            for (int nb = 0; nb < 8; nb++){
                bf8 bb = *(const bf8*)&bt[nb*16 + lc][ks*32 + quad*8];
                acc[0][nb] = MFMA(a0, bb, acc[0][nb]);
                acc[1][nb] = MFMA(a1, bb, acc[1][nb]);
            }
        }
        __syncthreads();
    }
    #pragma unroll
    for (int mb = 0; mb < 2; mb++){
        #pragma unroll
        for (int r = 0; r < 4; r++){
            int row = wv_*32 + mb*16 + quad*4 + r;
            int s_ = sperm[row];
            if (s_ < 0) continue;
            #pragma unroll
            for (int nb = 0; nb < 8; nb++){
                int col = c0 + nb*16 + lc;
                opre[((size_t)(b*Sc + s_))*Dc + col] = acc[mb][nb][r];
            }
        }
    }
}

// ---------------------------------------------------------------------------
// 11. final RMSNorm over D -> out
// ---------------------------------------------------------------------------
__global__ __launch_bounds__(256) void k_onorm(
    const float* __restrict__ opre, const float* __restrict__ anw,
    const int* __restrict__ mod, float* __restrict__ out)
{
    int row = blockIdx.x;
    int m = mod[row];
    int t = threadIdx.x;
    float val[4];
    float ss = 0.f;
    #pragma unroll
    for (int j=0;j<4;j++){
        val[j] = opre[(size_t)row*Dc + t + 256*j];
        ss += val[j]*val[j];
    }
    #pragma unroll
    for (int o=32;o>0;o>>=1) ss += __shfl_xor(ss, o, 64);
    __shared__ float red[4];
    int wid = t>>6, lane = t&63;
    if (lane==0) red[wid]=ss;
    __syncthreads();
    float tot = red[0]+red[1]+red[2]+red[3];
    float rms = rsqrtf(tot*(1.f/1024.f) + EPSc);
    #pragma unroll
    for (int j=0;j<4;j++)
        out[(size_t)row*Dc + t + 256*j] = val[j]*rms*anw[m*Dc + t + 256*j];
}

// ---------------------------------------------------------------------------
extern "C" void kernel_launch(void* const* d_in, const int* in_sizes, int n_in,
                              void* d_out, int out_size, void* d_ws, size_t ws_size,
                              hipStream_t stream)
{
    const float* x    = (const float*)d_in[0];
    const float* mask = (const float*)d_in[1];
    const int*   mod  = (const int*)  d_in[2];
    const float* Wq   = (const float*)d_in[3];
    const float* Wk   = (const float*)d_in[4];
    const float* Wv   = (const float*)d_in[5];
    const float* Wo   = (const float*)d_in[6];
    const float* qnw  = (const float*)d_in[7];
    const float* knw  = (const float*)d_in[8];
    const float* anw  = (const float*)d_in[9];

    float* out   = (float*)d_out;                 // [B,S,D]
    float* awout = out + (size_t)Bc*Sc*Dc;        // [B,S,S]

    float* ws = (float*)d_ws;
    // float-offset layout (bf16 buffers counted in float slots = elems/2)
    u16* qb   = (u16*)(ws + 0);          // 4.2M bf16   (opre aliases qb+kb later)
    u16* kb   = (u16*)(ws + 2097152);
    u16* vb   = (u16*)(ws + 4194304);
    u16* xb   = (u16*)(ws + 6291456);    // dead after k_qkv -> ctxb aliases
    u16* ctxb = xb;
    u16* vtb  = (u16*)(ws + 8388608);
    u16* wqT  = (u16*)(ws + 10485760);
    u16* wkT  = (u16*)(ws + 11534336);
    u16* wvT  = (u16*)(ws + 12582912);
    u16* woT  = (u16*)(ws + 13631488);
    float* mst = ws + 14680064;
    float* lst = ws + 14745600;
    int*   perm  = (int*)(ws + 14811136);
    int*   tmeta = perm + NTILES*TILE_R;
    float* opre  = ws;                    // 4.2M fp32 over qb+kb (dead by then)

    k_perm  <<<dim3(1),            256, 0, stream>>>(mod, perm, tmeta);
    k_f2b   <<<dim3(4096),         256, 0, stream>>>(x, xb, Bc*Sc*Dc);
    k_tcvt  <<<dim3(32,32,2),      256, 0, stream>>>(Wq, wqT);
    k_tcvt  <<<dim3(32,32,2),      256, 0, stream>>>(Wk, wkT);
    k_tcvt  <<<dim3(32,32,2),      256, 0, stream>>>(Wv, wvT);
    k_tcvt  <<<dim3(32,32,2),      256, 0, stream>>>(Wo, woT);
    k_qkv   <<<dim3(8,NTILES,3),   256, 0, stream>>>(xb, wqT, wkT, wvT, perm, tmeta, qb, kb, vb);
    k_qknorm<<<dim3(32768),        256, 0, stream>>>(qb, kb, qnw, knw, mod);
    k_vt    <<<dim3(16384),        256, 0, stream>>>(vb, vtb);
    k_stats <<<dim3(16,16,2),      256, 0, stream>>>(qb, kb, mask, mst, lst);
    k_attnw <<<dim3(16,16,2),      256, 0, stream>>>(qb, kb, mask, mst, lst, awout);
    k_flash <<<dim3(16,16,2),      256, 0, stream>>>(qb, kb, vtb, mask, mst, lst, ctxb);
    k_oproj <<<dim3(8,NTILES),     256, 0, stream>>>(ctxb, woT, perm, tmeta, opre);
    k_onorm <<<dim3(4096),         256, 0, stream>>>(opre, anw, mod, out);
}

// Round 4
// 549.013 us; speedup vs baseline: 3.6553x; 1.0454x over previous
//
#include <hip/hip_runtime.h>
#include <cstdint>

#define Bc  2
#define Sc  2048
#define Dc  1024
#define Ec  1024
#define Hc  16
#define HDc 64
#define TTc (Bc*Sc)
#define TILE_R 128
#define NTILES 36
#define EPSc 1e-5f

typedef unsigned short u16;
using bf8   = __attribute__((ext_vector_type(8))) short;
using f32x4 = __attribute__((ext_vector_type(4))) float;
#define MFMA(a,b,c) __builtin_amdgcn_mfma_f32_16x16x32_bf16(a,b,c,0,0,0)

static __device__ __forceinline__ u16 f2b(float f){
    return (u16)((__float_as_uint(f) + 0x8000u) >> 16);
}
static __device__ __forceinline__ float b2f(u16 s){
    return __uint_as_float(((unsigned)s) << 16);
}

// ---------------------------------------------------------------------------
// 1. modality-sorted token permutation, 128-padded segments per (b,m)
// ---------------------------------------------------------------------------
__global__ void k_perm(const int* __restrict__ mod, int* __restrict__ perm,
                       int* __restrict__ tmeta)
{
    __shared__ int cnt[4], segstart[4];
    int t = threadIdx.x;
    if (t < 4) cnt[t] = 0;
    __syncthreads();
    for (int i = t; i < TTc; i += 256){
        int b = i >> 11; int m = mod[i];
        atomicAdd(&cnt[b*2+m], 1);
    }
    __syncthreads();
    if (t == 0){
        int off = 0;
        for (int i = 0; i < 4; i++){
            segstart[i] = off;
            int pad = ((cnt[i] + TILE_R - 1)/TILE_R)*TILE_R;
            for (int tt = off/TILE_R; tt < (off+pad)/TILE_R; tt++) tmeta[tt] = i;
            off += pad;
        }
        for (int tt = off/TILE_R; tt < NTILES; tt++) tmeta[tt] = -1;
    }
    __syncthreads();
    if (t < 4) cnt[t] = 0;
    for (int i = t; i < NTILES*TILE_R; i += 256) perm[i] = -1;
    __syncthreads();
    for (int i = t; i < TTc; i += 256){
        int b = i >> 11, s = i & 2047; int m = mod[i];
        int r = atomicAdd(&cnt[b*2+m], 1);
        perm[segstart[b*2+m] + r] = s;
    }
}

// ---------------------------------------------------------------------------
// 2. fp32 -> bf16 elementwise
// ---------------------------------------------------------------------------
__global__ __launch_bounds__(256) void k_f2b(const float* __restrict__ src,
                                             u16* __restrict__ dst, int n)
{
    int i = (blockIdx.x*256 + threadIdx.x)*4;
    if (i >= n) return;
    float4 v = *(const float4*)&src[i];
    ushort4 o;
    o.x = f2b(v.x); o.y = f2b(v.y); o.z = f2b(v.z); o.w = f2b(v.w);
    *(ushort4*)&dst[i] = o;
}

// ---------------------------------------------------------------------------
// 2b. zero a float buffer (awout must be zeroed: harness poisons d_out)
// ---------------------------------------------------------------------------
__global__ __launch_bounds__(256) void k_zero(float* __restrict__ p)
{
    int i = (blockIdx.x*256 + threadIdx.x)*4;
    *(float4*)&p[i] = make_float4(0.f,0.f,0.f,0.f);
}

// ---------------------------------------------------------------------------
// 3. transpose+convert one [2][1024][1024] weight: dst[m][j][i] = src[m][i][j]
// ---------------------------------------------------------------------------
__global__ __launch_bounds__(256) void k_tcvt(const float* __restrict__ src,
                                              u16* __restrict__ dst)
{
    int m = blockIdx.z;
    src += (size_t)m*1048576; dst += (size_t)m*1048576;
    __shared__ float sh[32][33];
    int t = threadIdx.x;
    int i0 = blockIdx.x*32, j0 = blockIdx.y*32;
    {
        int i = t >> 3, j4 = (t & 7)*4;
        *(float4*)&sh[i][j4] = *(const float4*)&src[(size_t)(i0+i)*1024 + j0 + j4];
    }
    __syncthreads();
    {
        int j = t >> 3, i4 = (t & 7)*4;
        ushort4 o;
        o.x = f2b(sh[i4+0][j]); o.y = f2b(sh[i4+1][j]);
        o.z = f2b(sh[i4+2][j]); o.w = f2b(sh[i4+3][j]);
        *(ushort4*)&dst[(size_t)(j0+j)*1024 + i0 + i4] = o;
    }
}

// ---------------------------------------------------------------------------
// 4. QKV projection, MFMA. grid (8, NTILES, 3)
// ---------------------------------------------------------------------------
__global__ __launch_bounds__(256) void k_qkv(
    const u16* __restrict__ xb, const u16* __restrict__ wqT,
    const u16* __restrict__ wkT, const u16* __restrict__ wvT,
    const int* __restrict__ perm, const int* __restrict__ tmeta,
    u16* __restrict__ qb, u16* __restrict__ kb, u16* __restrict__ vb)
{
    int meta = tmeta[blockIdx.y];
    if (meta < 0) return;
    int b = meta >> 1, m = meta & 1;
    const u16* W = (blockIdx.z==0 ? wqT : (blockIdx.z==1 ? wkT : wvT)) + (size_t)m*Ec*Dc;
    u16* outp    = (blockIdx.z==0 ? qb  : (blockIdx.z==1 ? kb  : vb));
    int c0 = blockIdx.x*128;
    int t = threadIdx.x, lane = t & 63, wv_ = t >> 6;
    int quad = lane >> 4, lc = lane & 15;

    __shared__ u16 at[128][72];
    __shared__ u16 bt[128][72];
    __shared__ int sperm[128];
    if (t < 128) sperm[t] = perm[blockIdx.y*128 + t];
    f32x4 acc[2][8];
    #pragma unroll
    for (int i=0;i<2;i++)
        #pragma unroll
        for (int j=0;j<8;j++) acc[i][j] = (f32x4){0.f,0.f,0.f,0.f};
    __syncthreads();

    int rr = t >> 1, hf = t & 1;
    for (int d0 = 0; d0 < Dc; d0 += 64){
        int s_ = sperm[rr];
        if (s_ >= 0){
            const u16* src = xb + ((size_t)(b*Sc + s_))*Dc + d0 + hf*32;
            *(uint4*)&at[rr][hf*32]      = *(const uint4*)(src);
            *(uint4*)&at[rr][hf*32 + 8]  = *(const uint4*)(src + 8);
            *(uint4*)&at[rr][hf*32 + 16] = *(const uint4*)(src + 16);
            *(uint4*)&at[rr][hf*32 + 24] = *(const uint4*)(src + 24);
        } else {
            uint4 z = make_uint4(0,0,0,0);
            *(uint4*)&at[rr][hf*32]      = z;
            *(uint4*)&at[rr][hf*32 + 8]  = z;
            *(uint4*)&at[rr][hf*32 + 16] = z;
            *(uint4*)&at[rr][hf*32 + 24] = z;
        }
        const u16* wsrc = W + (size_t)(c0 + rr)*Dc + d0 + hf*32;
        *(uint4*)&bt[rr][hf*32]      = *(const uint4*)(wsrc);
        *(uint4*)&bt[rr][hf*32 + 8]  = *(const uint4*)(wsrc + 8);
        *(uint4*)&bt[rr][hf*32 + 16] = *(const uint4*)(wsrc + 16);
        *(uint4*)&bt[rr][hf*32 + 24] = *(const uint4*)(wsrc + 24);
        __syncthreads();
        #pragma unroll
        for (int ks = 0; ks < 2; ks++){
            bf8 a0 = *(const bf8*)&at[wv_*32 + lc][ks*32 + quad*8];
            bf8 a1 = *(const bf8*)&at[wv_*32 + 16 + lc][ks*32 + quad*8];
            #pragma unroll
            for (int nb = 0; nb < 8; nb++){
                bf8 bb = *(const bf8*)&bt[nb*16 + lc][ks*32 + quad*8];
                acc[0][nb] = MFMA(a0, bb, acc[0][nb]);
                acc[1][nb] = MFMA(a1, bb, acc[1][nb]);
            }
        }
        __syncthreads();
    }
    int h0 = c0 >> 6;
    #pragma unroll
    for (int mb = 0; mb < 2; mb++){
        #pragma unroll
        for (int r = 0; r < 4; r++){
            int row = wv_*32 + mb*16 + quad*4 + r;
            int s_ = sperm[row];
            if (s_ < 0) continue;
            #pragma unroll
            for (int nb = 0; nb < 8; nb++){
                int col = nb*16 + lc;
                int h = h0 + (col >> 6), hd = col & 63;
                outp[(((size_t)(b*Hc + h))*Sc + s_)*HDc + hd] = f2b(acc[mb][nb][r]);
            }
        }
    }
}

// ---------------------------------------------------------------------------
// 5. per-head RMSNorm on bf16 q and k, in place
// ---------------------------------------------------------------------------
__global__ __launch_bounds__(256) void k_qknorm(
    u16* __restrict__ qb, u16* __restrict__ kb,
    const float* __restrict__ qnw, const float* __restrict__ knw,
    const int* __restrict__ mod)
{
    int wid = threadIdx.x >> 6, lane = threadIdx.x & 63;
    int row = blockIdx.x*4 + wid;
    int isK = row >= 65536;
    int r = row & 65535;
    u16* buf = isK ? kb : qb;
    const float* wv = isK ? knw : qnw;
    int s = r & 2047;
    int b = r >> 15;
    int m = mod[b*Sc + s];
    float val = b2f(buf[(size_t)r*HDc + lane]);
    float ss = val*val;
    #pragma unroll
    for (int o = 32; o > 0; o >>= 1) ss += __shfl_xor(ss, o, 64);
    float rms = rsqrtf(ss*(1.f/64.f) + EPSc);
    buf[(size_t)r*HDc + lane] = f2b(val * rms * wv[m*HDc + lane]);
}

// ---------------------------------------------------------------------------
// 6. V transpose: vb [B,H,S,HD] -> vtb [B,H,HD,S]
// ---------------------------------------------------------------------------
__global__ __launch_bounds__(256) void k_vt(const u16* __restrict__ vb,
                                            u16* __restrict__ vtb)
{
    int idx = blockIdx.x*256 + threadIdx.x;
    int s = idx & 2047;
    int rest = idx >> 11;
    int hd = rest & 63;
    int bh = rest >> 6;
    vtb[idx] = vb[((size_t)bh*Sc + s)*HDc + hd];
}

// ---------------------------------------------------------------------------
// 7. softmax stats, split-K x4. grid (16, 16, 8): z = b*4 + chunk.
//    mask staged in LDS (bf16). Partial (m,l) -> pmst/plst.
// ---------------------------------------------------------------------------
__global__ __launch_bounds__(256) void k_stats(
    const u16* __restrict__ qb, const u16* __restrict__ kb,
    const u16* __restrict__ maskb, float* __restrict__ pmst,
    float* __restrict__ plst)
{
    int qs0 = blockIdx.x*128, h = blockIdx.y;
    int b = blockIdx.z >> 2, ch = blockIdx.z & 3;
    int t = threadIdx.x, lane = t & 63, wv_ = t >> 6;
    int quad = lane >> 4, lc = lane & 15;
    __shared__ u16 qt[128][72];
    __shared__ u16 kt[64][72];
    __shared__ u16 mt[128][72];
    const u16* qp = qb + ((size_t)(b*Hc+h))*Sc*HDc;
    const u16* kp = kb + ((size_t)(b*Hc+h))*Sc*HDc;
    {
        int rr = t >> 1, cc = (t & 1)*32;
        const u16* s = qp + (size_t)(qs0+rr)*HDc + cc;
        *(uint4*)&qt[rr][cc]    = *(const uint4*)(s);
        *(uint4*)&qt[rr][cc+8]  = *(const uint4*)(s+8);
        *(uint4*)&qt[rr][cc+16] = *(const uint4*)(s+16);
        *(uint4*)&qt[rr][cc+24] = *(const uint4*)(s+24);
    }
    float rm[8], rl[8];
    #pragma unroll
    for (int i=0;i<8;i++){ rm[i] = -1.0e30f; rl[i] = 0.f; }

    int kc0 = ch*512;
    for (int kc = kc0; kc < kc0 + 512; kc += 64){
        __syncthreads();
        {
            int rr = t >> 2, cc = (t & 3)*16;
            const u16* s = kp + (size_t)(kc+rr)*HDc + cc;
            *(uint4*)&kt[rr][cc]   = *(const uint4*)(s);
            *(uint4*)&kt[rr][cc+8] = *(const uint4*)(s+8);
            int rr2 = t >> 1, cc2 = (t & 1)*32;
            const u16* ms = maskb + (size_t)(qs0+rr2)*Sc + kc + cc2;
            *(uint4*)&mt[rr2][cc2]    = *(const uint4*)(ms);
            *(uint4*)&mt[rr2][cc2+8]  = *(const uint4*)(ms+8);
            *(uint4*)&mt[rr2][cc2+16] = *(const uint4*)(ms+16);
            *(uint4*)&mt[rr2][cc2+24] = *(const uint4*)(ms+24);
        }
        __syncthreads();
        f32x4 acc[2][4];
        #pragma unroll
        for (int i=0;i<2;i++)
            #pragma unroll
            for (int j=0;j<4;j++) acc[i][j] = (f32x4){0.f,0.f,0.f,0.f};
        #pragma unroll
        for (int ks = 0; ks < 2; ks++){
            bf8 a0 = *(const bf8*)&qt[wv_*32 + lc][ks*32 + quad*8];
            bf8 a1 = *(const bf8*)&qt[wv_*32 + 16 + lc][ks*32 + quad*8];
            #pragma unroll
            for (int nb = 0; nb < 4; nb++){
                bf8 bb = *(const bf8*)&kt[nb*16 + lc][ks*32 + quad*8];
                acc[0][nb] = MFMA(a0, bb, acc[0][nb]);
                acc[1][nb] = MFMA(a1, bb, acc[1][nb]);
            }
        }
        #pragma unroll
        for (int mb = 0; mb < 2; mb++){
            #pragma unroll
            for (int r = 0; r < 4; r++){
                int row = wv_*32 + mb*16 + quad*4 + r;
                float sv[4];
                #pragma unroll
                for (int nb = 0; nb < 4; nb++)
                    sv[nb] = acc[mb][nb][r]*0.125f + b2f(mt[row][nb*16 + lc]);
                float mx = fmaxf(fmaxf(sv[0],sv[1]), fmaxf(sv[2],sv[3]));
                int slot = mb*4 + r;
                float nm = fmaxf(rm[slot], mx);
                float a2 = rl[slot]*__expf(rm[slot]-nm);
                #pragma unroll
                for (int nb = 0; nb < 4; nb++) a2 += __expf(sv[nb]-nm);
                rm[slot] = nm; rl[slot] = a2;
            }
        }
    }
    #pragma unroll
    for (int slot = 0; slot < 8; slot++){
        #pragma unroll
        for (int o = 1; o < 16; o <<= 1){
            float m2 = __shfl_xor(rm[slot], o, 64);
            float l2 = __shfl_xor(rl[slot], o, 64);
            float nm = fmaxf(rm[slot], m2);
            rl[slot] = rl[slot]*__expf(rm[slot]-nm) + l2*__expf(m2-nm);
            rm[slot] = nm;
        }
    }
    if (lc == 0){
        #pragma unroll
        for (int mb = 0; mb < 2; mb++){
            #pragma unroll
            for (int r = 0; r < 4; r++){
                int row = qs0 + wv_*32 + mb*16 + quad*4 + r;
                size_t idx = (size_t)ch*65536 + ((size_t)(b*Hc+h))*Sc + row;
                pmst[idx] = rm[mb*4+r];
                plst[idx] = rl[mb*4+r];
            }
        }
    }
}

// ---------------------------------------------------------------------------
// 7b. merge split-K partials -> mst/lst
// ---------------------------------------------------------------------------
__global__ __launch_bounds__(256) void k_merge(
    const float* __restrict__ pmst, const float* __restrict__ plst,
    float* __restrict__ mst, float* __restrict__ lst)
{
    int r = blockIdx.x*256 + threadIdx.x;   // 0..65535
    float M = -1.0e30f, L = 0.f;
    #pragma unroll
    for (int c = 0; c < 4; c++){
        float m2 = pmst[(size_t)c*65536 + r];
        float l2 = plst[(size_t)c*65536 + r];
        float nm = fmaxf(M, m2);
        L = L*__expf(M-nm) + l2*__expf(m2-nm);
        M = nm;
    }
    mst[r] = M; lst[r] = L;
}

// ---------------------------------------------------------------------------
// 8. attn_weights, split over h x2. grid (16, 16, 4): z = b*2 + hgrp.
//    atomicAdd partial sums into zeroed awout.
// ---------------------------------------------------------------------------
__global__ __launch_bounds__(256) void k_attnw(
    const u16* __restrict__ qb, const u16* __restrict__ kb,
    const u16* __restrict__ maskb, const float* __restrict__ mst,
    const float* __restrict__ lst, float* __restrict__ awout)
{
    int qs0 = blockIdx.x*128, ks0 = blockIdx.y*128;
    int b = blockIdx.z >> 1, hg = blockIdx.z & 1;
    int t = threadIdx.x, lane = t & 63, wv_ = t >> 6;
    int quad = lane >> 4, lc = lane & 15;
    __shared__ u16 qt[128][72];
    __shared__ u16 kt[128][72];
    __shared__ float sm[128], sli[128];
    f32x4 T[2][8];
    #pragma unroll
    for (int i=0;i<2;i++)
        #pragma unroll
        for (int j=0;j<8;j++) T[i][j] = (f32x4){0.f,0.f,0.f,0.f};

    for (int h = hg*8; h < hg*8 + 8; h++){
        __syncthreads();
        const u16* qp = qb + ((size_t)(b*Hc+h))*Sc*HDc;
        const u16* kp = kb + ((size_t)(b*Hc+h))*Sc*HDc;
        {
            int rr = t >> 1, cc = (t & 1)*32;
            const u16* s1 = qp + (size_t)(qs0+rr)*HDc + cc;
            *(uint4*)&qt[rr][cc]    = *(const uint4*)(s1);
            *(uint4*)&qt[rr][cc+8]  = *(const uint4*)(s1+8);
            *(uint4*)&qt[rr][cc+16] = *(const uint4*)(s1+16);
            *(uint4*)&qt[rr][cc+24] = *(const uint4*)(s1+24);
            const u16* s2 = kp + (size_t)(ks0+rr)*HDc + cc;
            *(uint4*)&kt[rr][cc]    = *(const uint4*)(s2);
            *(uint4*)&kt[rr][cc+8]  = *(const uint4*)(s2+8);
            *(uint4*)&kt[rr][cc+16] = *(const uint4*)(s2+16);
            *(uint4*)&kt[rr][cc+24] = *(const uint4*)(s2+24);
        }
        if (t < 128){
            sm[t]  = mst[((size_t)(b*Hc+h))*Sc + qs0 + t];
            sli[t] = 1.f / lst[((size_t)(b*Hc+h))*Sc + qs0 + t];
        }
        __syncthreads();
        f32x4 acc[2][8];
        #pragma unroll
        for (int i=0;i<2;i++)
            #pragma unroll
            for (int j=0;j<8;j++) acc[i][j] = (f32x4){0.f,0.f,0.f,0.f};
        #pragma unroll
        for (int ks = 0; ks < 2; ks++){
            bf8 a0 = *(const bf8*)&qt[wv_*32 + lc][ks*32 + quad*8];
            bf8 a1 = *(const bf8*)&qt[wv_*32 + 16 + lc][ks*32 + quad*8];
            #pragma unroll
            for (int nb = 0; nb < 8; nb++){
                bf8 bb = *(const bf8*)&kt[nb*16 + lc][ks*32 + quad*8];
                acc[0][nb] = MFMA(a0, bb, acc[0][nb]);
                acc[1][nb] = MFMA(a1, bb, acc[1][nb]);
            }
        }
        #pragma unroll
        for (int mb = 0; mb < 2; mb++){
            #pragma unroll
            for (int r = 0; r < 4; r++){
                int row = wv_*32 + mb*16 + quad*4 + r;
                float mm = sm[row], li = sli[row];
                #pragma unroll
                for (int nb = 0; nb < 8; nb++){
                    float s = acc[mb][nb][r]*0.125f;
                    T[mb][nb][r] += __expf(fminf(s - mm, 60.f))*li;
                }
            }
        }
    }
    #pragma unroll
    for (int mb = 0; mb < 2; mb++){
        #pragma unroll
        for (int r = 0; r < 4; r++){
            int gq = qs0 + wv_*32 + mb*16 + quad*4 + r;
            #pragma unroll
            for (int nb = 0; nb < 8; nb++){
                int gk = ks0 + nb*16 + lc;
                float mk = b2f(maskb[(size_t)gq*Sc + gk]);
                atomicAdd(&awout[(size_t)b*Sc*Sc + (size_t)gq*Sc + gk],
                          T[mb][nb][r]*__expf(mk)*(1.f/16.f));
            }
        }
    }
}

// ---------------------------------------------------------------------------
// 9. flash PV with precomputed stats; mask staged in LDS (bf16).
//    grid (qtile16, h16, b2).
// ---------------------------------------------------------------------------
__global__ __launch_bounds__(256) void k_flash(
    const u16* __restrict__ qb, const u16* __restrict__ kb,
    const u16* __restrict__ vtb, const u16* __restrict__ maskb,
    const float* __restrict__ mst, const float* __restrict__ lst,
    u16* __restrict__ ctxb)
{
    int qs0 = blockIdx.x*128, h = blockIdx.y, b = blockIdx.z;
    int t = threadIdx.x, lane = t & 63, wv_ = t >> 6;
    int quad = lane >> 4, lc = lane & 15;
    __shared__ u16 qt[128][72];
    __shared__ u16 kt[64][72];
    __shared__ u16 vt[64][72];
    __shared__ u16 pt[128][72];
    __shared__ u16 mt[128][72];
    __shared__ float sm[128], sli[128];
    const u16* qp  = qb  + ((size_t)(b*Hc+h))*Sc*HDc;
    const u16* kp  = kb  + ((size_t)(b*Hc+h))*Sc*HDc;
    const u16* vtp = vtb + ((size_t)(b*Hc+h))*HDc*Sc;
    {
        int rr = t >> 1, cc = (t & 1)*32;
        const u16* s1 = qp + (size_t)(qs0+rr)*HDc + cc;
        *(uint4*)&qt[rr][cc]    = *(const uint4*)(s1);
        *(uint4*)&qt[rr][cc+8]  = *(const uint4*)(s1+8);
        *(uint4*)&qt[rr][cc+16] = *(const uint4*)(s1+16);
        *(uint4*)&qt[rr][cc+24] = *(const uint4*)(s1+24);
    }
    if (t < 128){
        sm[t]  = mst[((size_t)(b*Hc+h))*Sc + qs0 + t];
        sli[t] = 1.f / lst[((size_t)(b*Hc+h))*Sc + qs0 + t];
    }
    f32x4 oacc[2][4];
    #pragma unroll
    for (int i=0;i<2;i++)
        #pragma unroll
        for (int j=0;j<4;j++) oacc[i][j] = (f32x4){0.f,0.f,0.f,0.f};

    for (int kc = 0; kc < Sc; kc += 64){
        __syncthreads();
        {
            int rr = t >> 2, cc = (t & 3)*16;
            const u16* s1 = kp + (size_t)(kc+rr)*HDc + cc;
            *(uint4*)&kt[rr][cc]   = *(const uint4*)(s1);
            *(uint4*)&kt[rr][cc+8] = *(const uint4*)(s1+8);
            const u16* s2 = vtp + (size_t)rr*Sc + kc + cc;
            *(uint4*)&vt[rr][cc]   = *(const uint4*)(s2);
            *(uint4*)&vt[rr][cc+8] = *(const uint4*)(s2+8);
            int rr2 = t >> 1, cc2 = (t & 1)*32;
            const u16* ms = maskb + (size_t)(qs0+rr2)*Sc + kc + cc2;
            *(uint4*)&mt[rr2][cc2]    = *(const uint4*)(ms);
            *(uint4*)&mt[rr2][cc2+8]  = *(const uint4*)(ms+8);
            *(uint4*)&mt[rr2][cc2+16] = *(const uint4*)(ms+16);
            *(uint4*)&mt[rr2][cc2+24] = *(const uint4*)(ms+24);
        }
        __syncthreads();
        f32x4 acc[2][4];
        #pragma unroll
        for (int i=0;i<2;i++)
            #pragma unroll
            for (int j=0;j<4;j++) acc[i][j] = (f32x4){0.f,0.f,0.f,0.f};
        #pragma unroll
        for (int ks = 0; ks < 2; ks++){
            bf8 a0 = *(const bf8*)&qt[wv_*32 + lc][ks*32 + quad*8];
            bf8 a1 = *(const bf8*)&qt[wv_*32 + 16 + lc][ks*32 + quad*8];
            #pragma unroll
            for (int nb = 0; nb < 4; nb++){
                bf8 bb = *(const bf8*)&kt[nb*16 + lc][ks*32 + quad*8];
                acc[0][nb] = MFMA(a0, bb, acc[0][nb]);
                acc[1][nb] = MFMA(a1, bb, acc[1][nb]);
            }
        }
        #pragma unroll
        for (int mb = 0; mb < 2; mb++){
            #pragma unroll
            for (int r = 0; r < 4; r++){
                int row = wv_*32 + mb*16 + quad*4 + r;
                float mm = sm[row], li = sli[row];
                #pragma unroll
                for (int nb = 0; nb < 4; nb++){
                    float s = acc[mb][nb][r]*0.125f + b2f(mt[row][nb*16 + lc]);
                    pt[row][nb*16 + lc] = f2b(__expf(s - mm)*li);
                }
            }
        }
        __syncthreads();
        #pragma unroll
        for (int ks = 0; ks < 2; ks++){
            bf8 a0 = *(const bf8*)&pt[wv_*32 + lc][ks*32 + quad*8];
            bf8 a1 = *(const bf8*)&pt[wv_*32 + 16 + lc][ks*32 + quad*8];
            #pragma unroll
            for (int nb = 0; nb < 4; nb++){
                bf8 bb = *(const bf8*)&vt[nb*16 + lc][ks*32 + quad*8];
                oacc[0][nb] = MFMA(a0, bb, oacc[0][nb]);
                oacc[1][nb] = MFMA(a1, bb, oacc[1][nb]);
            }
        }
    }
    #pragma unroll
    for (int mb = 0; mb < 2; mb++){
        #pragma unroll
        for (int r = 0; r < 4; r++){
            int tok = qs0 + wv_*32 + mb*16 + quad*4 + r;
            #pragma unroll
            for (int nb = 0; nb < 4; nb++){
                int hd = nb*16 + lc;
                ctxb[((size_t)(b*Sc + tok))*Ec + h*HDc + hd] = f2b(oacc[mb][nb][r]);
            }
        }
    }
}

// ---------------------------------------------------------------------------
// 10. output projection, MFMA. grid (8, NTILES).
// ---------------------------------------------------------------------------
__global__ __launch_bounds__(256) void k_oproj(
    const u16* __restrict__ ctxb, const u16* __restrict__ woT,
    const int* __restrict__ perm, const int* __restrict__ tmeta,
    float* __restrict__ opre)
{
    int meta = tmeta[blockIdx.y];
    if (meta < 0) return;
    int b = meta >> 1, m = meta & 1;
    const u16* W = woT + (size_t)m*Ec*Dc;
    int c0 = blockIdx.x*128;
    int t = threadIdx.x, lane = t & 63, wv_ = t >> 6;
    int quad = lane >> 4, lc = lane & 15;
    __shared__ u16 at[128][72];
    __shared__ u16 bt[128][72];
    __shared__ int sperm[128];
    if (t < 128) sperm[t] = perm[blockIdx.y*128 + t];
    f32x4 acc[2][8];
    #pragma unroll
    for (int i=0;i<2;i++)
        #pragma unroll
        for (int j=0;j<8;j++) acc[i][j] = (f32x4){0.f,0.f,0.f,0.f};
    __syncthreads();

    int rr = t >> 1, hf = t & 1;
    for (int d0 = 0; d0 < Ec; d0 += 64){
        int s_ = sperm[rr];
        if (s_ >= 0){
            const u16* src = ctxb + ((size_t)(b*Sc + s_))*Ec + d0 + hf*32;
            *(uint4*)&at[rr][hf*32]      = *(const uint4*)(src);
            *(uint4*)&at[rr][hf*32 + 8]  = *(const uint4*)(src + 8);
            *(uint4*)&at[rr][hf*32 + 16] = *(const uint4*)(src + 16);
            *(uint4*)&at[rr][hf*32 + 24] = *(const uint4*)(src + 24);
        } else {
            uint4 z = make_uint4(0,0,0,0);
            *(uint4*)&at[rr][hf*32]      = z;
            *(uint4*)&at[rr][hf*32 + 8]  = z;
            *(uint4*)&at[rr][hf*32 + 16] = z;
            *(uint4*)&at[rr][hf*32 + 24] = z;
        }
        const u16* wsrc = W + (size_t)(c0 + rr)*Ec + d0 + hf*32;
        *(uint4*)&bt[rr][hf*32]      = *(const uint4*)(wsrc);
        *(uint4*)&bt[rr][hf*32 + 8]  = *(const uint4*)(wsrc + 8);
        *(uint4*)&bt[rr][hf*32 + 16] = *(const uint4*)(wsrc + 16);
        *(uint4*)&bt[rr][hf*32 + 24] = *(const uint4*)(wsrc + 24);
        __syncthreads();
        #pragma unroll
        for (int ks = 0; ks < 2; ks++){
            bf8 a0 = *(const bf8*)&at[wv_*32 + lc][ks*32 + quad*8];
            bf8 a1 = *(const bf8*)&at[wv_*32 + 16 + lc][ks*32 + quad*8];
            #pragma unroll
            for (int nb = 0; nb < 8; nb++){
                bf8 bb = *(const bf8*)&bt[nb*16 + lc][ks*32 + quad*8];
                acc[0][nb] = MFMA(a0, bb, acc[0][nb]);
                acc[1][nb] = MFMA(a1, bb, acc[1][nb]);
            }
        }
        __syncthreads();
    }
    #pragma unroll
    for (int mb = 0; mb < 2; mb++){
        #pragma unroll
        for (int r = 0; r < 4; r++){
            int row = wv_*32 + mb*16 + quad*4 + r;
            int s_ = sperm[row];
            if (s_ < 0) continue;
            #pragma unroll
            for (int nb = 0; nb < 8; nb++){
                int col = c0 + nb*16 + lc;
                opre[((size_t)(b*Sc + s_))*Dc + col] = acc[mb][nb][r];
            }
        }
    }
}

// ---------------------------------------------------------------------------
// 11. final RMSNorm over D -> out
// ---------------------------------------------------------------------------
__global__ __launch_bounds__(256) void k_onorm(
    const float* __restrict__ opre, const float* __restrict__ anw,
    const int* __restrict__ mod, float* __restrict__ out)
{
    int row = blockIdx.x;
    int m = mod[row];
    int t = threadIdx.x;
    float val[4];
    float ss = 0.f;
    #pragma unroll
    for (int j=0;j<4;j++){
        val[j] = opre[(size_t)row*Dc + t + 256*j];
        ss += val[j]*val[j];
    }
    #pragma unroll
    for (int o=32;o>0;o>>=1) ss += __shfl_xor(ss, o, 64);
    __shared__ float red[4];
    int wid = t>>6, lane = t&63;
    if (lane==0) red[wid]=ss;
    __syncthreads();
    float tot = red[0]+red[1]+red[2]+red[3];
    float rms = rsqrtf(tot*(1.f/1024.f) + EPSc);
    #pragma unroll
    for (int j=0;j<4;j++)
        out[(size_t)row*Dc + t + 256*j] = val[j]*rms*anw[m*Dc + t + 256*j];
}

// ---------------------------------------------------------------------------
extern "C" void kernel_launch(void* const* d_in, const int* in_sizes, int n_in,
                              void* d_out, int out_size, void* d_ws, size_t ws_size,
                              hipStream_t stream)
{
    const float* x    = (const float*)d_in[0];
    const float* mask = (const float*)d_in[1];
    const int*   mod  = (const int*)  d_in[2];
    const float* Wq   = (const float*)d_in[3];
    const float* Wk   = (const float*)d_in[4];
    const float* Wv   = (const float*)d_in[5];
    const float* Wo   = (const float*)d_in[6];
    const float* qnw  = (const float*)d_in[7];
    const float* knw  = (const float*)d_in[8];
    const float* anw  = (const float*)d_in[9];

    float* out   = (float*)d_out;                 // [B,S,D]
    float* awout = out + (size_t)Bc*Sc*Dc;        // [B,S,S]

    float* ws = (float*)d_ws;
    u16* qb    = (u16*)(ws + 0);
    u16* kb    = (u16*)(ws + 2097152);
    u16* vb    = (u16*)(ws + 4194304);
    u16* xb    = (u16*)(ws + 6291456);    // dead after k_qkv -> ctxb aliases
    u16* ctxb  = xb;
    u16* vtb   = (u16*)(ws + 8388608);
    u16* wqT   = (u16*)(ws + 10485760);
    u16* wkT   = (u16*)(ws + 11534336);
    u16* wvT   = (u16*)(ws + 12582912);
    u16* woT   = (u16*)(ws + 13631488);
    float* mst = ws + 14680064;
    float* lst = ws + 14745600;
    float* pmst= ws + 14811136;           // 4*65536
    float* plst= ws + 15073280;           // 4*65536
    u16* maskb = (u16*)(ws + 15335424);   // S*S bf16 = 2,097,152 float slots
    int* perm  = (int*)(ws + 17432576);
    int* tmeta = perm + NTILES*TILE_R;
    float* opre = ws;                     // aliases qb+kb (dead by then)

    k_perm  <<<dim3(1),            256, 0, stream>>>(mod, perm, tmeta);
    k_f2b   <<<dim3(4096),         256, 0, stream>>>(x, xb, Bc*Sc*Dc);
    k_f2b   <<<dim3(4096),         256, 0, stream>>>(mask, maskb, Sc*Sc);
    k_zero  <<<dim3(8192),         256, 0, stream>>>(awout);
    k_tcvt  <<<dim3(32,32,2),      256, 0, stream>>>(Wq, wqT);
    k_tcvt  <<<dim3(32,32,2),      256, 0, stream>>>(Wk, wkT);
    k_tcvt  <<<dim3(32,32,2),      256, 0, stream>>>(Wv, wvT);
    k_tcvt  <<<dim3(32,32,2),      256, 0, stream>>>(Wo, woT);
    k_qkv   <<<dim3(8,NTILES,3),   256, 0, stream>>>(xb, wqT, wkT, wvT, perm, tmeta, qb, kb, vb);
    k_qknorm<<<dim3(32768),        256, 0, stream>>>(qb, kb, qnw, knw, mod);
    k_vt    <<<dim3(16384),        256, 0, stream>>>(vb, vtb);
    k_stats <<<dim3(16,16,8),      256, 0, stream>>>(qb, kb, maskb, pmst, plst);
    k_merge <<<dim3(256),          256, 0, stream>>>(pmst, plst, mst, lst);
    k_attnw <<<dim3(16,16,4),      256, 0, stream>>>(qb, kb, maskb, mst, lst, awout);
    k_flash <<<dim3(16,16,2),      256, 0, stream>>>(qb, kb, vtb, maskb, mst, lst, ctxb);
    k_oproj <<<dim3(8,NTILES),     256, 0, stream>>>(ctxb, woT, perm, tmeta, opre);
    k_onorm <<<dim3(4096),         256, 0, stream>>>(opre, anw, mod, out);
}

// Round 5
// 530.998 us; speedup vs baseline: 3.7793x; 1.0339x over previous
//
#include <hip/hip_runtime.h>
#include <cstdint>

#define Bc  2
#define Sc  2048
#define Dc  1024
#define Ec  1024
#define Hc  16
#define HDc 64
#define TTc (Bc*Sc)
#define TILE_R 128
#define NTILES 36
#define EPSc 1e-5f

typedef unsigned short u16;
using bf8   = __attribute__((ext_vector_type(8))) short;
using f32x4 = __attribute__((ext_vector_type(4))) float;
#define MFMA(a,b,c) __builtin_amdgcn_mfma_f32_16x16x32_bf16(a,b,c,0,0,0)

static __device__ __forceinline__ u16 f2b(float f){
    return (u16)((__float_as_uint(f) + 0x8000u) >> 16);
}
static __device__ __forceinline__ float b2f(u16 s){
    return __uint_as_float(((unsigned)s) << 16);
}

// ---------------------------------------------------------------------------
// 1. modality-sorted token permutation, 128-padded segments per (b,m)
// ---------------------------------------------------------------------------
__global__ void k_perm(const int* __restrict__ mod, int* __restrict__ perm,
                       int* __restrict__ tmeta)
{
    __shared__ int cnt[4], segstart[4];
    int t = threadIdx.x;
    if (t < 4) cnt[t] = 0;
    __syncthreads();
    for (int i = t; i < TTc; i += 256){
        int b = i >> 11; int m = mod[i];
        atomicAdd(&cnt[b*2+m], 1);
    }
    __syncthreads();
    if (t == 0){
        int off = 0;
        for (int i = 0; i < 4; i++){
            segstart[i] = off;
            int pad = ((cnt[i] + TILE_R - 1)/TILE_R)*TILE_R;
            for (int tt = off/TILE_R; tt < (off+pad)/TILE_R; tt++) tmeta[tt] = i;
            off += pad;
        }
        for (int tt = off/TILE_R; tt < NTILES; tt++) tmeta[tt] = -1;
    }
    __syncthreads();
    if (t < 4) cnt[t] = 0;
    for (int i = t; i < NTILES*TILE_R; i += 256) perm[i] = -1;
    __syncthreads();
    for (int i = t; i < TTc; i += 256){
        int b = i >> 11, s = i & 2047; int m = mod[i];
        int r = atomicAdd(&cnt[b*2+m], 1);
        perm[segstart[b*2+m] + r] = s;
    }
}

// ---------------------------------------------------------------------------
// 2. fp32 -> bf16 elementwise
// ---------------------------------------------------------------------------
__global__ __launch_bounds__(256) void k_f2b(const float* __restrict__ src,
                                             u16* __restrict__ dst, int n)
{
    int i = (blockIdx.x*256 + threadIdx.x)*4;
    if (i >= n) return;
    float4 v = *(const float4*)&src[i];
    ushort4 o;
    o.x = f2b(v.x); o.y = f2b(v.y); o.z = f2b(v.z); o.w = f2b(v.w);
    *(ushort4*)&dst[i] = o;
}

// ---------------------------------------------------------------------------
// 2b. zero a float buffer
// ---------------------------------------------------------------------------
__global__ __launch_bounds__(256) void k_zero(float* __restrict__ p)
{
    int i = (blockIdx.x*256 + threadIdx.x)*4;
    *(float4*)&p[i] = make_float4(0.f,0.f,0.f,0.f);
}

// ---------------------------------------------------------------------------
// 3. transpose+convert all four weights in one launch; grid (32,32,8)
// ---------------------------------------------------------------------------
__global__ __launch_bounds__(256) void k_tcvt(
    const float* __restrict__ s0, const float* __restrict__ s1,
    const float* __restrict__ s2, const float* __restrict__ s3,
    u16* __restrict__ d0, u16* __restrict__ d1,
    u16* __restrict__ d2, u16* __restrict__ d3)
{
    int wsel = blockIdx.z >> 1, m = blockIdx.z & 1;
    const float* src = (wsel==0?s0:wsel==1?s1:wsel==2?s2:s3) + (size_t)m*1048576;
    u16*       dst = (wsel==0?d0:wsel==1?d1:wsel==2?d2:d3) + (size_t)m*1048576;
    __shared__ float sh[32][33];
    int t = threadIdx.x;
    int i0 = blockIdx.x*32, j0 = blockIdx.y*32;
    {
        int i = t >> 3, j4 = (t & 7)*4;
        *(float4*)&sh[i][j4] = *(const float4*)&src[(size_t)(i0+i)*1024 + j0 + j4];
    }
    __syncthreads();
    {
        int j = t >> 3, i4 = (t & 7)*4;
        ushort4 o;
        o.x = f2b(sh[i4+0][j]); o.y = f2b(sh[i4+1][j]);
        o.z = f2b(sh[i4+2][j]); o.w = f2b(sh[i4+3][j]);
        *(ushort4*)&dst[(size_t)(j0+j)*1024 + i0 + i4] = o;
    }
}

// ---------------------------------------------------------------------------
// 4. QKV projection, MFMA, with fused per-head RMSNorm for Q and K.
//    grid (8, NTILES, 3)
// ---------------------------------------------------------------------------
__global__ __launch_bounds__(256) void k_qkv(
    const u16* __restrict__ xb, const u16* __restrict__ wqT,
    const u16* __restrict__ wkT, const u16* __restrict__ wvT,
    const int* __restrict__ perm, const int* __restrict__ tmeta,
    const float* __restrict__ qnw, const float* __restrict__ knw,
    u16* __restrict__ qb, u16* __restrict__ kb, u16* __restrict__ vb)
{
    int meta = tmeta[blockIdx.y];
    if (meta < 0) return;
    int b = meta >> 1, m = meta & 1;
    const u16* W = (blockIdx.z==0 ? wqT : (blockIdx.z==1 ? wkT : wvT)) + (size_t)m*Ec*Dc;
    u16* outp    = (blockIdx.z==0 ? qb  : (blockIdx.z==1 ? kb  : vb));
    int c0 = blockIdx.x*128;
    int t = threadIdx.x, lane = t & 63, wv_ = t >> 6;
    int quad = lane >> 4, lc = lane & 15;

    __shared__ u16 at[128][72];
    __shared__ u16 bt[128][72];
    __shared__ int sperm[128];
    if (t < 128) sperm[t] = perm[blockIdx.y*128 + t];
    f32x4 acc[2][8];
    #pragma unroll
    for (int i=0;i<2;i++)
        #pragma unroll
        for (int j=0;j<8;j++) acc[i][j] = (f32x4){0.f,0.f,0.f,0.f};
    __syncthreads();

    int rr = t >> 1, hf = t & 1;
    for (int d0 = 0; d0 < Dc; d0 += 64){
        int s_ = sperm[rr];
        if (s_ >= 0){
            const u16* src = xb + ((size_t)(b*Sc + s_))*Dc + d0 + hf*32;
            *(uint4*)&at[rr][hf*32]      = *(const uint4*)(src);
            *(uint4*)&at[rr][hf*32 + 8]  = *(const uint4*)(src + 8);
            *(uint4*)&at[rr][hf*32 + 16] = *(const uint4*)(src + 16);
            *(uint4*)&at[rr][hf*32 + 24] = *(const uint4*)(src + 24);
        } else {
            uint4 z = make_uint4(0,0,0,0);
            *(uint4*)&at[rr][hf*32]      = z;
            *(uint4*)&at[rr][hf*32 + 8]  = z;
            *(uint4*)&at[rr][hf*32 + 16] = z;
            *(uint4*)&at[rr][hf*32 + 24] = z;
        }
        const u16* wsrc = W + (size_t)(c0 + rr)*Dc + d0 + hf*32;
        *(uint4*)&bt[rr][hf*32]      = *(const uint4*)(wsrc);
        *(uint4*)&bt[rr][hf*32 + 8]  = *(const uint4*)(wsrc + 8);
        *(uint4*)&bt[rr][hf*32 + 16] = *(const uint4*)(wsrc + 16);
        *(uint4*)&bt[rr][hf*32 + 24] = *(const uint4*)(wsrc + 24);
        __syncthreads();
        #pragma unroll
        for (int ks = 0; ks < 2; ks++){
            bf8 a0 = *(const bf8*)&at[wv_*32 + lc][ks*32 + quad*8];
            bf8 a1 = *(const bf8*)&at[wv_*32 + 16 + lc][ks*32 + quad*8];
            #pragma unroll
            for (int nb = 0; nb < 8; nb++){
                bf8 bb = *(const bf8*)&bt[nb*16 + lc][ks*32 + quad*8];
                acc[0][nb] = MFMA(a0, bb, acc[0][nb]);
                acc[1][nb] = MFMA(a1, bb, acc[1][nb]);
            }
        }
        __syncthreads();
    }

    // fused per-head RMSNorm for q/k (fp32, pre-rounding).
    if (blockIdx.z < 2){
        const float* nw = (blockIdx.z==0 ? qnw : knw) + m*HDc;
        float w0 = nw[lc], w1 = nw[16+lc], w2 = nw[32+lc], w3 = nw[48+lc];
        #pragma unroll
        for (int mb = 0; mb < 2; mb++){
            #pragma unroll
            for (int r = 0; r < 4; r++){
                #pragma unroll
                for (int g = 0; g < 2; g++){
                    float ss = 0.f;
                    #pragma unroll
                    for (int j = 0; j < 4; j++){
                        float v2 = acc[mb][g*4+j][r];
                        ss += v2*v2;
                    }
                    ss += __shfl_xor(ss, 1, 64);
                    ss += __shfl_xor(ss, 2, 64);
                    ss += __shfl_xor(ss, 4, 64);
                    ss += __shfl_xor(ss, 8, 64);
                    float rs = rsqrtf(ss*(1.f/64.f) + EPSc);
                    acc[mb][g*4+0][r] *= rs*w0;
                    acc[mb][g*4+1][r] *= rs*w1;
                    acc[mb][g*4+2][r] *= rs*w2;
                    acc[mb][g*4+3][r] *= rs*w3;
                }
            }
        }
    }

    int h0 = c0 >> 6;
    #pragma unroll
    for (int mb = 0; mb < 2; mb++){
        #pragma unroll
        for (int r = 0; r < 4; r++){
            int row = wv_*32 + mb*16 + quad*4 + r;
            int s_ = sperm[row];
            if (s_ < 0) continue;
            #pragma unroll
            for (int nb = 0; nb < 8; nb++){
                int col = nb*16 + lc;
                int h = h0 + (col >> 6), hd = col & 63;
                outp[(((size_t)(b*Hc + h))*Sc + s_)*HDc + hd] = f2b(acc[mb][nb][r]);
            }
        }
    }
}

// ---------------------------------------------------------------------------
// 6. V transpose via LDS tiles: vb [BH][S][HD] -> vtb [BH][HD][S]
//    grid (S/64=32, BH=32)
// ---------------------------------------------------------------------------
__global__ __launch_bounds__(256) void k_vt(const u16* __restrict__ vb,
                                            u16* __restrict__ vtb)
{
    __shared__ u16 sh[64][72];
    int t = threadIdx.x;
    int s0 = blockIdx.x*64, bh = blockIdx.y;
    {
        int rr = t >> 2, cc = (t & 3)*16;
        const u16* src = vb + ((size_t)bh*Sc + s0 + rr)*HDc + cc;
        *(uint4*)&sh[rr][cc]   = *(const uint4*)(src);
        *(uint4*)&sh[rr][cc+8] = *(const uint4*)(src+8);
    }
    __syncthreads();
    {
        int hd = t >> 2, sc = (t & 3)*16;
        u16 tmp[16];
        #pragma unroll
        for (int j = 0; j < 16; j++) tmp[j] = sh[sc+j][hd];
        u16* dst = vtb + ((size_t)bh*HDc + hd)*Sc + s0 + sc;
        *(uint4*)(dst)   = *(const uint4*)&tmp[0];
        *(uint4*)(dst+8) = *(const uint4*)&tmp[8];
    }
}

// ---------------------------------------------------------------------------
// 7. softmax stats, split-K x4, Q fragments direct from global.
//    grid (16, 16, 8): z = b*4 + chunk
// ---------------------------------------------------------------------------
__global__ __launch_bounds__(256) void k_stats(
    const u16* __restrict__ qb, const u16* __restrict__ kb,
    const u16* __restrict__ maskb, float* __restrict__ pmst,
    float* __restrict__ plst)
{
    int qs0 = blockIdx.x*128, h = blockIdx.y;
    int b = blockIdx.z >> 2, ch = blockIdx.z & 3;
    int t = threadIdx.x, lane = t & 63, wv_ = t >> 6;
    int quad = lane >> 4, lc = lane & 15;
    __shared__ u16 kt[64][72];
    __shared__ u16 mt[128][72];
    const u16* qp = qb + ((size_t)(b*Hc+h))*Sc*HDc;
    const u16* kp = kb + ((size_t)(b*Hc+h))*Sc*HDc;
    bf8 aq[2][2];
    #pragma unroll
    for (int mb = 0; mb < 2; mb++)
        #pragma unroll
        for (int ks = 0; ks < 2; ks++)
            aq[mb][ks] = *(const bf8*)(qp + (size_t)(qs0 + wv_*32 + mb*16 + lc)*HDc
                                          + ks*32 + quad*8);
    float rm[8], rl[8];
    #pragma unroll
    for (int i=0;i<8;i++){ rm[i] = -1.0e30f; rl[i] = 0.f; }

    int kc0 = ch*512;
    for (int kc = kc0; kc < kc0 + 512; kc += 64){
        __syncthreads();
        {
            int rr = t >> 2, cc = (t & 3)*16;
            const u16* s = kp + (size_t)(kc+rr)*HDc + cc;
            *(uint4*)&kt[rr][cc]   = *(const uint4*)(s);
            *(uint4*)&kt[rr][cc+8] = *(const uint4*)(s+8);
            int rr2 = t >> 1, cc2 = (t & 1)*32;
            const u16* ms = maskb + (size_t)(qs0+rr2)*Sc + kc + cc2;
            *(uint4*)&mt[rr2][cc2]    = *(const uint4*)(ms);
            *(uint4*)&mt[rr2][cc2+8]  = *(const uint4*)(ms+8);
            *(uint4*)&mt[rr2][cc2+16] = *(const uint4*)(ms+16);
            *(uint4*)&mt[rr2][cc2+24] = *(const uint4*)(ms+24);
        }
        __syncthreads();
        f32x4 acc[2][4];
        #pragma unroll
        for (int i=0;i<2;i++)
            #pragma unroll
            for (int j=0;j<4;j++) acc[i][j] = (f32x4){0.f,0.f,0.f,0.f};
        #pragma unroll
        for (int ks = 0; ks < 2; ks++){
            #pragma unroll
            for (int nb = 0; nb < 4; nb++){
                bf8 bb = *(const bf8*)&kt[nb*16 + lc][ks*32 + quad*8];
                acc[0][nb] = MFMA(aq[0][ks], bb, acc[0][nb]);
                acc[1][nb] = MFMA(aq[1][ks], bb, acc[1][nb]);
            }
        }
        #pragma unroll
        for (int mb = 0; mb < 2; mb++){
            #pragma unroll
            for (int r = 0; r < 4; r++){
                int row = wv_*32 + mb*16 + quad*4 + r;
                float sv[4];
                #pragma unroll
                for (int nb = 0; nb < 4; nb++)
                    sv[nb] = acc[mb][nb][r]*0.125f + b2f(mt[row][nb*16 + lc]);
                float mx = fmaxf(fmaxf(sv[0],sv[1]), fmaxf(sv[2],sv[3]));
                int slot = mb*4 + r;
                float nm = fmaxf(rm[slot], mx);
                float a2 = rl[slot]*__expf(rm[slot]-nm);
                #pragma unroll
                for (int nb = 0; nb < 4; nb++) a2 += __expf(sv[nb]-nm);
                rm[slot] = nm; rl[slot] = a2;
            }
        }
    }
    #pragma unroll
    for (int slot = 0; slot < 8; slot++){
        #pragma unroll
        for (int o = 1; o < 16; o <<= 1){
            float m2 = __shfl_xor(rm[slot], o, 64);
            float l2 = __shfl_xor(rl[slot], o, 64);
            float nm = fmaxf(rm[slot], m2);
            rl[slot] = rl[slot]*__expf(rm[slot]-nm) + l2*__expf(m2-nm);
            rm[slot] = nm;
        }
    }
    if (lc == 0){
        #pragma unroll
        for (int mb = 0; mb < 2; mb++){
            #pragma unroll
            for (int r = 0; r < 4; r++){
                int row = qs0 + wv_*32 + mb*16 + quad*4 + r;
                size_t idx = (size_t)ch*65536 + ((size_t)(b*Hc+h))*Sc + row;
                pmst[idx] = rm[mb*4+r];
                plst[idx] = rl[mb*4+r];
            }
        }
    }
}

// ---------------------------------------------------------------------------
// 7b. merge split-K partials -> mst/lst
// ---------------------------------------------------------------------------
__global__ __launch_bounds__(256) void k_merge(
    const float* __restrict__ pmst, const float* __restrict__ plst,
    float* __restrict__ mst, float* __restrict__ lst)
{
    int r = blockIdx.x*256 + threadIdx.x;
    float M = -1.0e30f, L = 0.f;
    #pragma unroll
    for (int c = 0; c < 4; c++){
        float m2 = pmst[(size_t)c*65536 + r];
        float l2 = plst[(size_t)c*65536 + r];
        float nm = fmaxf(M, m2);
        L = L*__expf(M-nm) + l2*__expf(m2-nm);
        M = nm;
    }
    mst[r] = M; lst[r] = L;
}

// ---------------------------------------------------------------------------
// 8. attn_weights: q-tile 64, split h x2. grid (32, 16, 4): z = b*2 + hgrp.
//    Q fragments direct from global; only K tile in LDS.
// ---------------------------------------------------------------------------
__global__ __launch_bounds__(256) void k_attnw(
    const u16* __restrict__ qb, const u16* __restrict__ kb,
    const u16* __restrict__ maskb, const float* __restrict__ mst,
    const float* __restrict__ lst, float* __restrict__ awout)
{
    int qs0 = blockIdx.x*64, ks0 = blockIdx.y*128;
    int b = blockIdx.z >> 1, hg = blockIdx.z & 1;
    int t = threadIdx.x, lane = t & 63, wv_ = t >> 6;
    int quad = lane >> 4, lc = lane & 15;
    __shared__ u16 kt[128][72];
    __shared__ float sm[64], sli[64];
    f32x4 T[8];
    #pragma unroll
    for (int j=0;j<8;j++) T[j] = (f32x4){0.f,0.f,0.f,0.f};

    for (int h = hg*8; h < hg*8 + 8; h++){
        __syncthreads();
        const u16* qp = qb + ((size_t)(b*Hc+h))*Sc*HDc;
        const u16* kp = kb + ((size_t)(b*Hc+h))*Sc*HDc;
        bf8 aq[2];
        #pragma unroll
        for (int ks = 0; ks < 2; ks++)
            aq[ks] = *(const bf8*)(qp + (size_t)(qs0 + wv_*16 + lc)*HDc + ks*32 + quad*8);
        {
            int rr = t >> 1, cc = (t & 1)*32;
            const u16* s2 = kp + (size_t)(ks0+rr)*HDc + cc;
            *(uint4*)&kt[rr][cc]    = *(const uint4*)(s2);
            *(uint4*)&kt[rr][cc+8]  = *(const uint4*)(s2+8);
            *(uint4*)&kt[rr][cc+16] = *(const uint4*)(s2+16);
            *(uint4*)&kt[rr][cc+24] = *(const uint4*)(s2+24);
        }
        if (t < 64){
            sm[t]  = mst[((size_t)(b*Hc+h))*Sc + qs0 + t];
            sli[t] = 1.f / lst[((size_t)(b*Hc+h))*Sc + qs0 + t];
        }
        __syncthreads();
        f32x4 acc[8];
        #pragma unroll
        for (int j=0;j<8;j++) acc[j] = (f32x4){0.f,0.f,0.f,0.f};
        #pragma unroll
        for (int ks = 0; ks < 2; ks++){
            #pragma unroll
            for (int nb = 0; nb < 8; nb++){
                bf8 bb = *(const bf8*)&kt[nb*16 + lc][ks*32 + quad*8];
                acc[nb] = MFMA(aq[ks], bb, acc[nb]);
            }
        }
        #pragma unroll
        for (int r = 0; r < 4; r++){
            int row = wv_*16 + quad*4 + r;
            float mm = sm[row], li = sli[row];
            #pragma unroll
            for (int nb = 0; nb < 8; nb++){
                float s = acc[nb][r]*0.125f;
                T[nb][r] += __expf(fminf(s - mm, 60.f))*li;
            }
        }
    }
    #pragma unroll
    for (int r = 0; r < 4; r++){
        int gq = qs0 + wv_*16 + quad*4 + r;
        #pragma unroll
        for (int nb = 0; nb < 8; nb++){
            int gk = ks0 + nb*16 + lc;
            float mk = b2f(maskb[(size_t)gq*Sc + gk]);
            atomicAdd(&awout[(size_t)b*Sc*Sc + (size_t)gq*Sc + gk],
                      T[nb][r]*__expf(mk)*(1.f/16.f));
        }
    }
}

// ---------------------------------------------------------------------------
// 9. flash PV with precomputed stats: q-tile 64, Q fragments from global,
//    mask/P share one LDS buffer. grid (32, 16, 2).
// ---------------------------------------------------------------------------
__global__ __launch_bounds__(256) void k_flash(
    const u16* __restrict__ qb, const u16* __restrict__ kb,
    const u16* __restrict__ vtb, const u16* __restrict__ maskb,
    const float* __restrict__ mst, const float* __restrict__ lst,
    u16* __restrict__ ctxb)
{
    int qs0 = blockIdx.x*64, h = blockIdx.y, b = blockIdx.z;
    int t = threadIdx.x, lane = t & 63, wv_ = t >> 6;
    int quad = lane >> 4, lc = lane & 15;
    __shared__ u16 kt[64][72];
    __shared__ u16 vt[64][72];
    __shared__ u16 mpt[64][72];     // mask tile, overwritten in place by P
    __shared__ float sm[64], sli[64];
    const u16* qp  = qb  + ((size_t)(b*Hc+h))*Sc*HDc;
    const u16* kp  = kb  + ((size_t)(b*Hc+h))*Sc*HDc;
    const u16* vtp = vtb + ((size_t)(b*Hc+h))*HDc*Sc;
    bf8 aq[2];
    #pragma unroll
    for (int ks = 0; ks < 2; ks++)
        aq[ks] = *(const bf8*)(qp + (size_t)(qs0 + wv_*16 + lc)*HDc + ks*32 + quad*8);
    if (t < 64){
        sm[t]  = mst[((size_t)(b*Hc+h))*Sc + qs0 + t];
        sli[t] = 1.f / lst[((size_t)(b*Hc+h))*Sc + qs0 + t];
    }
    f32x4 oacc[4];
    #pragma unroll
    for (int j=0;j<4;j++) oacc[j] = (f32x4){0.f,0.f,0.f,0.f};

    for (int kc = 0; kc < Sc; kc += 64){
        __syncthreads();
        {
            int rr = t >> 2, cc = (t & 3)*16;
            const u16* s1 = kp + (size_t)(kc+rr)*HDc + cc;
            *(uint4*)&kt[rr][cc]   = *(const uint4*)(s1);
            *(uint4*)&kt[rr][cc+8] = *(const uint4*)(s1+8);
            const u16* s2 = vtp + (size_t)rr*Sc + kc + cc;
            *(uint4*)&vt[rr][cc]   = *(const uint4*)(s2);
            *(uint4*)&vt[rr][cc+8] = *(const uint4*)(s2+8);
            const u16* ms = maskb + (size_t)(qs0+rr)*Sc + kc + cc;
            *(uint4*)&mpt[rr][cc]   = *(const uint4*)(ms);
            *(uint4*)&mpt[rr][cc+8] = *(const uint4*)(ms+8);
        }
        __syncthreads();
        f32x4 acc[4];
        #pragma unroll
        for (int j=0;j<4;j++) acc[j] = (f32x4){0.f,0.f,0.f,0.f};
        #pragma unroll
        for (int ks = 0; ks < 2; ks++){
            #pragma unroll
            for (int nb = 0; nb < 4; nb++){
                bf8 bb = *(const bf8*)&kt[nb*16 + lc][ks*32 + quad*8];
                acc[nb] = MFMA(aq[ks], bb, acc[nb]);
            }
        }
        #pragma unroll
        for (int r = 0; r < 4; r++){
            int row = wv_*16 + quad*4 + r;
            float mm = sm[row], li = sli[row];
            #pragma unroll
            for (int nb = 0; nb < 4; nb++){
                int col = nb*16 + lc;
                float s = acc[nb][r]*0.125f + b2f(mpt[row][col]);
                mpt[row][col] = f2b(__expf(s - mm)*li);
            }
        }
        __syncthreads();
        #pragma unroll
        for (int ks = 0; ks < 2; ks++){
            bf8 ap = *(const bf8*)&mpt[wv_*16 + lc][ks*32 + quad*8];
            #pragma unroll
            for (int nb = 0; nb < 4; nb++){
                bf8 bb = *(const bf8*)&vt[nb*16 + lc][ks*32 + quad*8];
                oacc[nb] = MFMA(ap, bb, oacc[nb]);
            }
        }
    }
    #pragma unroll
    for (int r = 0; r < 4; r++){
        int tok = qs0 + wv_*16 + quad*4 + r;
        #pragma unroll
        for (int nb = 0; nb < 4; nb++){
            int hd = nb*16 + lc;
            ctxb[((size_t)(b*Sc + tok))*Ec + h*HDc + hd] = f2b(oacc[nb][r]);
        }
    }
}

// ---------------------------------------------------------------------------
// 10. output projection, MFMA. grid (8, NTILES).
// ---------------------------------------------------------------------------
__global__ __launch_bounds__(256) void k_oproj(
    const u16* __restrict__ ctxb, const u16* __restrict__ woT,
    const int* __restrict__ perm, const int* __restrict__ tmeta,
    float* __restrict__ opre)
{
    int meta = tmeta[blockIdx.y];
    if (meta < 0) return;
    int b = meta >> 1, m = meta & 1;
    const u16* W = woT + (size_t)m*Ec*Dc;
    int c0 = blockIdx.x*128;
    int t = threadIdx.x, lane = t & 63, wv_ = t >> 6;
    int quad = lane >> 4, lc = lane & 15;
    __shared__ u16 at[128][72];
    __shared__ u16 bt[128][72];
    __shared__ int sperm[128];
    if (t < 128) sperm[t] = perm[blockIdx.y*128 + t];
    f32x4 acc[2][8];
    #pragma unroll
    for (int i=0;i<2;i++)
        #pragma unroll
        for (int j=0;j<8;j++) acc[i][j] = (f32x4){0.f,0.f,0.f,0.f};
    __syncthreads();

    int rr = t >> 1, hf = t & 1;
    for (int d0 = 0; d0 < Ec; d0 += 64){
        int s_ = sperm[rr];
        if (s_ >= 0){
            const u16* src = ctxb + ((size_t)(b*Sc + s_))*Ec + d0 + hf*32;
            *(uint4*)&at[rr][hf*32]      = *(const uint4*)(src);
            *(uint4*)&at[rr][hf*32 + 8]  = *(const uint4*)(src + 8);
            *(uint4*)&at[rr][hf*32 + 16] = *(const uint4*)(src + 16);
            *(uint4*)&at[rr][hf*32 + 24] = *(const uint4*)(src + 24);
        } else {
            uint4 z = make_uint4(0,0,0,0);
            *(uint4*)&at[rr][hf*32]      = z;
            *(uint4*)&at[rr][hf*32 + 8]  = z;
            *(uint4*)&at[rr][hf*32 + 16] = z;
            *(uint4*)&at[rr][hf*32 + 24] = z;
        }
        const u16* wsrc = W + (size_t)(c0 + rr)*Ec + d0 + hf*32;
        *(uint4*)&bt[rr][hf*32]      = *(const uint4*)(wsrc);
        *(uint4*)&bt[rr][hf*32 + 8]  = *(const uint4*)(wsrc + 8);
        *(uint4*)&bt[rr][hf*32 + 16] = *(const uint4*)(wsrc + 16);
        *(uint4*)&bt[rr][hf*32 + 24] = *(const uint4*)(wsrc + 24);
        __syncthreads();
        #pragma unroll
        for (int ks = 0; ks < 2; ks++){
            bf8 a0 = *(const bf8*)&at[wv_*32 + lc][ks*32 + quad*8];
            bf8 a1 = *(const bf8*)&at[wv_*32 + 16 + lc][ks*32 + quad*8];
            #pragma unroll
            for (int nb = 0; nb < 8; nb++){
                bf8 bb = *(const bf8*)&bt[nb*16 + lc][ks*32 + quad*8];
                acc[0][nb] = MFMA(a0, bb, acc[0][nb]);
                acc[1][nb] = MFMA(a1, bb, acc[1][nb]);
            }
        }
        __syncthreads();
    }
    #pragma unroll
    for (int mb = 0; mb < 2; mb++){
        #pragma unroll
        for (int r = 0; r < 4; r++){
            int row = wv_*32 + mb*16 + quad*4 + r;
            int s_ = sperm[row];
            if (s_ < 0) continue;
            #pragma unroll
            for (int nb = 0; nb < 8; nb++){
                int col = c0 + nb*16 + lc;
                opre[((size_t)(b*Sc + s_))*Dc + col] = acc[mb][nb][r];
            }
        }
    }
}

// ---------------------------------------------------------------------------
// 11. final RMSNorm over D -> out
// ---------------------------------------------------------------------------
__global__ __launch_bounds__(256) void k_onorm(
    const float* __restrict__ opre, const float* __restrict__ anw,
    const int* __restrict__ mod, float* __restrict__ out)
{
    int row = blockIdx.x;
    int m = mod[row];
    int t = threadIdx.x;
    float val[4];
    float ss = 0.f;
    #pragma unroll
    for (int j=0;j<4;j++){
        val[j] = opre[(size_t)row*Dc + t + 256*j];
        ss += val[j]*val[j];
    }
    #pragma unroll
    for (int o=32;o>0;o>>=1) ss += __shfl_xor(ss, o, 64);
    __shared__ float red[4];
    int wid = t>>6, lane = t&63;
    if (lane==0) red[wid]=ss;
    __syncthreads();
    float tot = red[0]+red[1]+red[2]+red[3];
    float rms = rsqrtf(tot*(1.f/1024.f) + EPSc);
    #pragma unroll
    for (int j=0;j<4;j++)
        out[(size_t)row*Dc + t + 256*j] = val[j]*rms*anw[m*Dc + t + 256*j];
}

// ---------------------------------------------------------------------------
extern "C" void kernel_launch(void* const* d_in, const int* in_sizes, int n_in,
                              void* d_out, int out_size, void* d_ws, size_t ws_size,
                              hipStream_t stream)
{
    const float* x    = (const float*)d_in[0];
    const float* mask = (const float*)d_in[1];
    const int*   mod  = (const int*)  d_in[2];
    const float* Wq   = (const float*)d_in[3];
    const float* Wk   = (const float*)d_in[4];
    const float* Wv   = (const float*)d_in[5];
    const float* Wo   = (const float*)d_in[6];
    const float* qnw  = (const float*)d_in[7];
    const float* knw  = (const float*)d_in[8];
    const float* anw  = (const float*)d_in[9];

    float* out   = (float*)d_out;                 // [B,S,D]
    float* awout = out + (size_t)Bc*Sc*Dc;        // [B,S,S]

    float* ws = (float*)d_ws;
    u16* qb    = (u16*)(ws + 0);
    u16* kb    = (u16*)(ws + 2097152);
    u16* vb    = (u16*)(ws + 4194304);
    u16* xb    = (u16*)(ws + 6291456);    // dead after k_qkv -> ctxb aliases
    u16* ctxb  = xb;
    u16* vtb   = (u16*)(ws + 8388608);
    u16* wqT   = (u16*)(ws + 10485760);
    u16* wkT   = (u16*)(ws + 11534336);
    u16* wvT   = (u16*)(ws + 12582912);
    u16* woT   = (u16*)(ws + 13631488);
    float* mst = ws + 14680064;
    float* lst = ws + 14745600;
    float* pmst= ws + 14811136;           // 4*65536
    float* plst= ws + 15073280;           // 4*65536
    u16* maskb = (u16*)(ws + 15335424);   // S*S bf16
    int* perm  = (int*)(ws + 17432576);
    int* tmeta = perm + NTILES*TILE_R;
    float* opre = ws;                     // aliases qb+kb (dead by then)

    k_perm  <<<dim3(1),            256, 0, stream>>>(mod, perm, tmeta);
    k_f2b   <<<dim3(4096),         256, 0, stream>>>(x, xb, Bc*Sc*Dc);
    k_f2b   <<<dim3(4096),         256, 0, stream>>>(mask, maskb, Sc*Sc);
    k_zero  <<<dim3(8192),         256, 0, stream>>>(awout);
    k_tcvt  <<<dim3(32,32,8),      256, 0, stream>>>(Wq, Wk, Wv, Wo, wqT, wkT, wvT, woT);
    k_qkv   <<<dim3(8,NTILES,3),   256, 0, stream>>>(xb, wqT, wkT, wvT, perm, tmeta,
                                                     qnw, knw, qb, kb, vb);
    k_vt    <<<dim3(32,32),        256, 0, stream>>>(vb, vtb);
    k_stats <<<dim3(16,16,8),      256, 0, stream>>>(qb, kb, maskb, pmst, plst);
    k_merge <<<dim3(256),          256, 0, stream>>>(pmst, plst, mst, lst);
    k_attnw <<<dim3(32,16,4),      256, 0, stream>>>(qb, kb, maskb, mst, lst, awout);
    k_flash <<<dim3(32,16,2),      256, 0, stream>>>(qb, kb, vtb, maskb, mst, lst, ctxb);
    k_oproj <<<dim3(8,NTILES),     256, 0, stream>>>(ctxb, woT, perm, tmeta, opre);
    k_onorm <<<dim3(4096),         256, 0, stream>>>(opre, anw, mod, out);
}

// Round 6
// 501.272 us; speedup vs baseline: 4.0035x; 1.0593x over previous
//
#include <hip/hip_runtime.h>
#include <cstdint>

#define Bc  2
#define Sc  2048
#define Dc  1024
#define Ec  1024
#define Hc  16
#define HDc 64
#define TTc (Bc*Sc)
#define TILE_R 128
#define NTILES 36
#define EPSc 1e-5f
#define LOG2E 1.44269504f
#define C2    (0.125f*LOG2E)

typedef unsigned short u16;
using bf8   = __attribute__((ext_vector_type(8))) short;
using f32x4 = __attribute__((ext_vector_type(4))) float;
#define MFMA(a,b,c) __builtin_amdgcn_mfma_f32_16x16x32_bf16(a,b,c,0,0,0)

static __device__ __forceinline__ u16 f2b(float f){
    return (u16)((__float_as_uint(f) + 0x8000u) >> 16);
}
static __device__ __forceinline__ float b2f(u16 s){
    return __uint_as_float(((unsigned)s) << 16);
}

// ---------------------------------------------------------------------------
// 1. modality-sorted token permutation, 128-padded segments per (b,m)
// ---------------------------------------------------------------------------
__global__ void k_perm(const int* __restrict__ mod, int* __restrict__ perm,
                       int* __restrict__ tmeta)
{
    __shared__ int cnt[4], segstart[4];
    int t = threadIdx.x;
    if (t < 4) cnt[t] = 0;
    __syncthreads();
    for (int i = t; i < TTc; i += 256){
        int b = i >> 11; int m = mod[i];
        atomicAdd(&cnt[b*2+m], 1);
    }
    __syncthreads();
    if (t == 0){
        int off = 0;
        for (int i = 0; i < 4; i++){
            segstart[i] = off;
            int pad = ((cnt[i] + TILE_R - 1)/TILE_R)*TILE_R;
            for (int tt = off/TILE_R; tt < (off+pad)/TILE_R; tt++) tmeta[tt] = i;
            off += pad;
        }
        for (int tt = off/TILE_R; tt < NTILES; tt++) tmeta[tt] = -1;
    }
    __syncthreads();
    if (t < 4) cnt[t] = 0;
    for (int i = t; i < NTILES*TILE_R; i += 256) perm[i] = -1;
    __syncthreads();
    for (int i = t; i < TTc; i += 256){
        int b = i >> 11, s = i & 2047; int m = mod[i];
        int r = atomicAdd(&cnt[b*2+m], 1);
        perm[segstart[b*2+m] + r] = s;
    }
}

// ---------------------------------------------------------------------------
// 2. fp32 -> bf16 elementwise (optionally scaled)
// ---------------------------------------------------------------------------
__global__ __launch_bounds__(256) void k_f2b(const float* __restrict__ src,
                                             u16* __restrict__ dst, int n)
{
    int i = (blockIdx.x*256 + threadIdx.x)*4;
    if (i >= n) return;
    float4 v = *(const float4*)&src[i];
    ushort4 o;
    o.x = f2b(v.x); o.y = f2b(v.y); o.z = f2b(v.z); o.w = f2b(v.w);
    *(ushort4*)&dst[i] = o;
}

__global__ __launch_bounds__(256) void k_f2bs(const float* __restrict__ src,
                                              u16* __restrict__ dst, int n, float sc)
{
    int i = (blockIdx.x*256 + threadIdx.x)*4;
    if (i >= n) return;
    float4 v = *(const float4*)&src[i];
    ushort4 o;
    o.x = f2b(v.x*sc); o.y = f2b(v.y*sc); o.z = f2b(v.z*sc); o.w = f2b(v.w*sc);
    *(ushort4*)&dst[i] = o;
}

// ---------------------------------------------------------------------------
// 3. transpose+convert all four weights in one launch; grid (32,32,8)
// ---------------------------------------------------------------------------
__global__ __launch_bounds__(256) void k_tcvt(
    const float* __restrict__ s0, const float* __restrict__ s1,
    const float* __restrict__ s2, const float* __restrict__ s3,
    u16* __restrict__ d0, u16* __restrict__ d1,
    u16* __restrict__ d2, u16* __restrict__ d3)
{
    int wsel = blockIdx.z >> 1, m = blockIdx.z & 1;
    const float* src = (wsel==0?s0:wsel==1?s1:wsel==2?s2:s3) + (size_t)m*1048576;
    u16*       dst = (wsel==0?d0:wsel==1?d1:wsel==2?d2:d3) + (size_t)m*1048576;
    __shared__ float sh[32][33];
    int t = threadIdx.x;
    int i0 = blockIdx.x*32, j0 = blockIdx.y*32;
    {
        int i = t >> 3, j4 = (t & 7)*4;
        *(float4*)&sh[i][j4] = *(const float4*)&src[(size_t)(i0+i)*1024 + j0 + j4];
    }
    __syncthreads();
    {
        int j = t >> 3, i4 = (t & 7)*4;
        ushort4 o;
        o.x = f2b(sh[i4+0][j]); o.y = f2b(sh[i4+1][j]);
        o.z = f2b(sh[i4+2][j]); o.w = f2b(sh[i4+3][j]);
        *(ushort4*)&dst[(size_t)(j0+j)*1024 + i0 + i4] = o;
    }
}

// ---------------------------------------------------------------------------
// 4. QKV projection, MFMA, with fused per-head RMSNorm for Q and K.
//    grid (8, NTILES, 3)
// ---------------------------------------------------------------------------
__global__ __launch_bounds__(256) void k_qkv(
    const u16* __restrict__ xb, const u16* __restrict__ wqT,
    const u16* __restrict__ wkT, const u16* __restrict__ wvT,
    const int* __restrict__ perm, const int* __restrict__ tmeta,
    const float* __restrict__ qnw, const float* __restrict__ knw,
    u16* __restrict__ qb, u16* __restrict__ kb, u16* __restrict__ vb)
{
    int meta = tmeta[blockIdx.y];
    if (meta < 0) return;
    int b = meta >> 1, m = meta & 1;
    const u16* W = (blockIdx.z==0 ? wqT : (blockIdx.z==1 ? wkT : wvT)) + (size_t)m*Ec*Dc;
    u16* outp    = (blockIdx.z==0 ? qb  : (blockIdx.z==1 ? kb  : vb));
    int c0 = blockIdx.x*128;
    int t = threadIdx.x, lane = t & 63, wv_ = t >> 6;
    int quad = lane >> 4, lc = lane & 15;

    __shared__ u16 at[128][72];
    __shared__ u16 bt[128][72];
    __shared__ int sperm[128];
    if (t < 128) sperm[t] = perm[blockIdx.y*128 + t];
    f32x4 acc[2][8];
    #pragma unroll
    for (int i=0;i<2;i++)
        #pragma unroll
        for (int j=0;j<8;j++) acc[i][j] = (f32x4){0.f,0.f,0.f,0.f};
    __syncthreads();

    int rr = t >> 1, hf = t & 1;
    for (int d0 = 0; d0 < Dc; d0 += 64){
        int s_ = sperm[rr];
        if (s_ >= 0){
            const u16* src = xb + ((size_t)(b*Sc + s_))*Dc + d0 + hf*32;
            *(uint4*)&at[rr][hf*32]      = *(const uint4*)(src);
            *(uint4*)&at[rr][hf*32 + 8]  = *(const uint4*)(src + 8);
            *(uint4*)&at[rr][hf*32 + 16] = *(const uint4*)(src + 16);
            *(uint4*)&at[rr][hf*32 + 24] = *(const uint4*)(src + 24);
        } else {
            uint4 z = make_uint4(0,0,0,0);
            *(uint4*)&at[rr][hf*32]      = z;
            *(uint4*)&at[rr][hf*32 + 8]  = z;
            *(uint4*)&at[rr][hf*32 + 16] = z;
            *(uint4*)&at[rr][hf*32 + 24] = z;
        }
        const u16* wsrc = W + (size_t)(c0 + rr)*Dc + d0 + hf*32;
        *(uint4*)&bt[rr][hf*32]      = *(const uint4*)(wsrc);
        *(uint4*)&bt[rr][hf*32 + 8]  = *(const uint4*)(wsrc + 8);
        *(uint4*)&bt[rr][hf*32 + 16] = *(const uint4*)(wsrc + 16);
        *(uint4*)&bt[rr][hf*32 + 24] = *(const uint4*)(wsrc + 24);
        __syncthreads();
        #pragma unroll
        for (int ks = 0; ks < 2; ks++){
            bf8 a0 = *(const bf8*)&at[wv_*32 + lc][ks*32 + quad*8];
            bf8 a1 = *(const bf8*)&at[wv_*32 + 16 + lc][ks*32 + quad*8];
            #pragma unroll
            for (int nb = 0; nb < 8; nb++){
                bf8 bb = *(const bf8*)&bt[nb*16 + lc][ks*32 + quad*8];
                acc[0][nb] = MFMA(a0, bb, acc[0][nb]);
                acc[1][nb] = MFMA(a1, bb, acc[1][nb]);
            }
        }
        __syncthreads();
    }

    if (blockIdx.z < 2){
        const float* nw = (blockIdx.z==0 ? qnw : knw) + m*HDc;
        float w0 = nw[lc], w1 = nw[16+lc], w2 = nw[32+lc], w3 = nw[48+lc];
        #pragma unroll
        for (int mb = 0; mb < 2; mb++){
            #pragma unroll
            for (int r = 0; r < 4; r++){
                #pragma unroll
                for (int g = 0; g < 2; g++){
                    float ss = 0.f;
                    #pragma unroll
                    for (int j = 0; j < 4; j++){
                        float v2 = acc[mb][g*4+j][r];
                        ss += v2*v2;
                    }
                    ss += __shfl_xor(ss, 1, 64);
                    ss += __shfl_xor(ss, 2, 64);
                    ss += __shfl_xor(ss, 4, 64);
                    ss += __shfl_xor(ss, 8, 64);
                    float rs = rsqrtf(ss*(1.f/64.f) + EPSc);
                    acc[mb][g*4+0][r] *= rs*w0;
                    acc[mb][g*4+1][r] *= rs*w1;
                    acc[mb][g*4+2][r] *= rs*w2;
                    acc[mb][g*4+3][r] *= rs*w3;
                }
            }
        }
    }

    int h0 = c0 >> 6;
    #pragma unroll
    for (int mb = 0; mb < 2; mb++){
        #pragma unroll
        for (int r = 0; r < 4; r++){
            int row = wv_*32 + mb*16 + quad*4 + r;
            int s_ = sperm[row];
            if (s_ < 0) continue;
            #pragma unroll
            for (int nb = 0; nb < 8; nb++){
                int col = nb*16 + lc;
                int h = h0 + (col >> 6), hd = col & 63;
                outp[(((size_t)(b*Hc + h))*Sc + s_)*HDc + hd] = f2b(acc[mb][nb][r]);
            }
        }
    }
}

// ---------------------------------------------------------------------------
// 6. V transpose via LDS tiles: vb [BH][S][HD] -> vtb [BH][HD][S]
// ---------------------------------------------------------------------------
__global__ __launch_bounds__(256) void k_vt(const u16* __restrict__ vb,
                                            u16* __restrict__ vtb)
{
    __shared__ u16 sh[64][72];
    int t = threadIdx.x;
    int s0 = blockIdx.x*64, bh = blockIdx.y;
    {
        int rr = t >> 2, cc = (t & 3)*16;
        const u16* src = vb + ((size_t)bh*Sc + s0 + rr)*HDc + cc;
        *(uint4*)&sh[rr][cc]   = *(const uint4*)(src);
        *(uint4*)&sh[rr][cc+8] = *(const uint4*)(src+8);
    }
    __syncthreads();
    {
        int hd = t >> 2, sc = (t & 3)*16;
        u16 tmp[16];
        #pragma unroll
        for (int j = 0; j < 16; j++) tmp[j] = sh[sc+j][hd];
        u16* dst = vtb + ((size_t)bh*HDc + hd)*Sc + s0 + sc;
        *(uint4*)(dst)   = *(const uint4*)&tmp[0];
        *(uint4*)(dst+8) = *(const uint4*)&tmp[8];
    }
}

// ---------------------------------------------------------------------------
// 7. softmax stats (log2 domain), split-K x4. grid (16, 16, 8)
// ---------------------------------------------------------------------------
__global__ __launch_bounds__(256) void k_stats(
    const u16* __restrict__ qb, const u16* __restrict__ kb,
    const u16* __restrict__ maskb, float* __restrict__ pmst,
    float* __restrict__ plst)
{
    int qs0 = blockIdx.x*128, h = blockIdx.y;
    int b = blockIdx.z >> 2, ch = blockIdx.z & 3;
    int t = threadIdx.x, lane = t & 63, wv_ = t >> 6;
    int quad = lane >> 4, lc = lane & 15;
    __shared__ u16 kt[64][72];
    __shared__ u16 mt[128][72];
    const u16* qp = qb + ((size_t)(b*Hc+h))*Sc*HDc;
    const u16* kp = kb + ((size_t)(b*Hc+h))*Sc*HDc;
    bf8 aq[2][2];
    #pragma unroll
    for (int mb = 0; mb < 2; mb++)
        #pragma unroll
        for (int ks = 0; ks < 2; ks++)
            aq[mb][ks] = *(const bf8*)(qp + (size_t)(qs0 + wv_*32 + mb*16 + lc)*HDc
                                          + ks*32 + quad*8);
    float rm[8], rl[8];
    #pragma unroll
    for (int i=0;i<8;i++){ rm[i] = -1.0e30f; rl[i] = 0.f; }

    int kc0 = ch*512;
    for (int kc = kc0; kc < kc0 + 512; kc += 64){
        __syncthreads();
        {
            int rr = t >> 2, cc = (t & 3)*16;
            const u16* s = kp + (size_t)(kc+rr)*HDc + cc;
            *(uint4*)&kt[rr][cc]   = *(const uint4*)(s);
            *(uint4*)&kt[rr][cc+8] = *(const uint4*)(s+8);
            int rr2 = t >> 1, cc2 = (t & 1)*32;
            const u16* ms = maskb + (size_t)(qs0+rr2)*Sc + kc + cc2;
            *(uint4*)&mt[rr2][cc2]    = *(const uint4*)(ms);
            *(uint4*)&mt[rr2][cc2+8]  = *(const uint4*)(ms+8);
            *(uint4*)&mt[rr2][cc2+16] = *(const uint4*)(ms+16);
            *(uint4*)&mt[rr2][cc2+24] = *(const uint4*)(ms+24);
        }
        __syncthreads();
        f32x4 acc[2][4];
        #pragma unroll
        for (int i=0;i<2;i++)
            #pragma unroll
            for (int j=0;j<4;j++) acc[i][j] = (f32x4){0.f,0.f,0.f,0.f};
        #pragma unroll
        for (int ks = 0; ks < 2; ks++){
            #pragma unroll
            for (int nb = 0; nb < 4; nb++){
                bf8 bb = *(const bf8*)&kt[nb*16 + lc][ks*32 + quad*8];
                acc[0][nb] = MFMA(aq[0][ks], bb, acc[0][nb]);
                acc[1][nb] = MFMA(aq[1][ks], bb, acc[1][nb]);
            }
        }
        #pragma unroll
        for (int mb = 0; mb < 2; mb++){
            #pragma unroll
            for (int r = 0; r < 4; r++){
                int row = wv_*32 + mb*16 + quad*4 + r;
                float sv[4];
                #pragma unroll
                for (int nb = 0; nb < 4; nb++)
                    sv[nb] = fmaf(acc[mb][nb][r], C2, b2f(mt[row][nb*16 + lc]));
                float mx = fmaxf(fmaxf(sv[0],sv[1]), fmaxf(sv[2],sv[3]));
                int slot = mb*4 + r;
                float nm = fmaxf(rm[slot], mx);
                float a2 = rl[slot]*exp2f(rm[slot]-nm);
                #pragma unroll
                for (int nb = 0; nb < 4; nb++) a2 += exp2f(sv[nb]-nm);
                rm[slot] = nm; rl[slot] = a2;
            }
        }
    }
    #pragma unroll
    for (int slot = 0; slot < 8; slot++){
        #pragma unroll
        for (int o = 1; o < 16; o <<= 1){
            float m2 = __shfl_xor(rm[slot], o, 64);
            float l2 = __shfl_xor(rl[slot], o, 64);
            float nm = fmaxf(rm[slot], m2);
            rl[slot] = rl[slot]*exp2f(rm[slot]-nm) + l2*exp2f(m2-nm);
            rm[slot] = nm;
        }
    }
    if (lc == 0){
        #pragma unroll
        for (int mb = 0; mb < 2; mb++){
            #pragma unroll
            for (int r = 0; r < 4; r++){
                int row = qs0 + wv_*32 + mb*16 + quad*4 + r;
                size_t idx = (size_t)ch*65536 + ((size_t)(b*Hc+h))*Sc + row;
                pmst[idx] = rm[mb*4+r];
                plst[idx] = rl[mb*4+r];
            }
        }
    }
}

// ---------------------------------------------------------------------------
// 7b. merge split-K partials -> mst/lst (log2-domain m)
// ---------------------------------------------------------------------------
__global__ __launch_bounds__(256) void k_merge(
    const float* __restrict__ pmst, const float* __restrict__ plst,
    float* __restrict__ mst, float* __restrict__ lst)
{
    int r = blockIdx.x*256 + threadIdx.x;
    float M = -1.0e30f, L = 0.f;
    #pragma unroll
    for (int c = 0; c < 4; c++){
        float m2 = pmst[(size_t)c*65536 + r];
        float l2 = plst[(size_t)c*65536 + r];
        float nm = fmaxf(M, m2);
        L = L*exp2f(M-nm) + l2*exp2f(m2-nm);
        M = nm;
    }
    mst[r] = M; lst[r] = L;
}

// ---------------------------------------------------------------------------
// 8. attn_weights: q-tile 64, k-tile 64, loop all 16 h, NO atomics.
//    grid (32, 32, 2) = (q, k, b). Plain coalesced store.
// ---------------------------------------------------------------------------
__global__ __launch_bounds__(256) void k_attnw(
    const u16* __restrict__ qb, const u16* __restrict__ kb,
    const u16* __restrict__ maskb, const float* __restrict__ mst,
    const float* __restrict__ lst, float* __restrict__ awout)
{
    int qs0 = blockIdx.x*64, ks0 = blockIdx.y*64, b = blockIdx.z;
    int t = threadIdx.x, lane = t & 63, wv_ = t >> 6;
    int quad = lane >> 4, lc = lane & 15;
    __shared__ u16 kt[64][72];
    __shared__ float sm[64], sli[64];
    f32x4 T[4];
    #pragma unroll
    for (int j=0;j<4;j++) T[j] = (f32x4){0.f,0.f,0.f,0.f};

    for (int h = 0; h < Hc; h++){
        __syncthreads();
        const u16* qp = qb + ((size_t)(b*Hc+h))*Sc*HDc;
        const u16* kp = kb + ((size_t)(b*Hc+h))*Sc*HDc;
        bf8 aq[2];
        #pragma unroll
        for (int ks = 0; ks < 2; ks++)
            aq[ks] = *(const bf8*)(qp + (size_t)(qs0 + wv_*16 + lc)*HDc + ks*32 + quad*8);
        {
            int rr = t >> 2, cc = (t & 3)*16;
            const u16* s2 = kp + (size_t)(ks0+rr)*HDc + cc;
            *(uint4*)&kt[rr][cc]   = *(const uint4*)(s2);
            *(uint4*)&kt[rr][cc+8] = *(const uint4*)(s2+8);
        }
        if (t < 64){
            sm[t]  = mst[((size_t)(b*Hc+h))*Sc + qs0 + t];
            sli[t] = 1.f / lst[((size_t)(b*Hc+h))*Sc + qs0 + t];
        }
        __syncthreads();
        f32x4 acc[4];
        #pragma unroll
        for (int j=0;j<4;j++) acc[j] = (f32x4){0.f,0.f,0.f,0.f};
        #pragma unroll
        for (int ks = 0; ks < 2; ks++){
            #pragma unroll
            for (int nb = 0; nb < 4; nb++){
                bf8 bb = *(const bf8*)&kt[nb*16 + lc][ks*32 + quad*8];
                acc[nb] = MFMA(aq[ks], bb, acc[nb]);
            }
        }
        #pragma unroll
        for (int r = 0; r < 4; r++){
            int row = wv_*16 + quad*4 + r;
            float mm = sm[row], li = sli[row];
            #pragma unroll
            for (int nb = 0; nb < 4; nb++){
                float s = fminf(fmaf(acc[nb][r], C2, -mm), 80.f);
                T[nb][r] += exp2f(s)*li;
            }
        }
    }
    #pragma unroll
    for (int r = 0; r < 4; r++){
        int gq = qs0 + wv_*16 + quad*4 + r;
        #pragma unroll
        for (int nb = 0; nb < 4; nb++){
            int gk = ks0 + nb*16 + lc;
            float mk = b2f(maskb[(size_t)gq*Sc + gk]);   // mask*log2e
            awout[(size_t)b*Sc*Sc + (size_t)gq*Sc + gk]
                = T[nb][r]*exp2f(mk)*(1.f/16.f);
        }
    }
}

// ---------------------------------------------------------------------------
// 9. flash PV, split-K x2: grid (32, 16, 4): z = b*2 + half.
//    Partial bf16 ctx to c0/c1; exp2 epilogue (t<=0 guaranteed).
// ---------------------------------------------------------------------------
__global__ __launch_bounds__(256) void k_flash(
    const u16* __restrict__ qb, const u16* __restrict__ kb,
    const u16* __restrict__ vtb, const u16* __restrict__ maskb,
    const float* __restrict__ mst, const float* __restrict__ lst,
    u16* __restrict__ c0, u16* __restrict__ c1)
{
    int qs0 = blockIdx.x*64, h = blockIdx.y;
    int b = blockIdx.z >> 1, half = blockIdx.z & 1;
    u16* ctxh = half ? c1 : c0;
    int t = threadIdx.x, lane = t & 63, wv_ = t >> 6;
    int quad = lane >> 4, lc = lane & 15;
    __shared__ u16 kt[64][72];
    __shared__ u16 vt[64][72];
    __shared__ u16 mpt[64][72];
    __shared__ float sm[64], sli[64];
    const u16* qp  = qb  + ((size_t)(b*Hc+h))*Sc*HDc;
    const u16* kp  = kb  + ((size_t)(b*Hc+h))*Sc*HDc;
    const u16* vtp = vtb + ((size_t)(b*Hc+h))*HDc*Sc;
    bf8 aq[2];
    #pragma unroll
    for (int ks = 0; ks < 2; ks++)
        aq[ks] = *(const bf8*)(qp + (size_t)(qs0 + wv_*16 + lc)*HDc + ks*32 + quad*8);
    if (t < 64){
        sm[t]  = mst[((size_t)(b*Hc+h))*Sc + qs0 + t];
        sli[t] = 1.f / lst[((size_t)(b*Hc+h))*Sc + qs0 + t];
    }
    f32x4 oacc[4];
    #pragma unroll
    for (int j=0;j<4;j++) oacc[j] = (f32x4){0.f,0.f,0.f,0.f};

    int kc0 = half*1024;
    for (int kc = kc0; kc < kc0 + 1024; kc += 64){
        __syncthreads();
        {
            int rr = t >> 2, cc = (t & 3)*16;
            const u16* s1 = kp + (size_t)(kc+rr)*HDc + cc;
            *(uint4*)&kt[rr][cc]   = *(const uint4*)(s1);
            *(uint4*)&kt[rr][cc+8] = *(const uint4*)(s1+8);
            const u16* s2 = vtp + (size_t)rr*Sc + kc + cc;
            *(uint4*)&vt[rr][cc]   = *(const uint4*)(s2);
            *(uint4*)&vt[rr][cc+8] = *(const uint4*)(s2+8);
            const u16* ms = maskb + (size_t)(qs0+rr)*Sc + kc + cc;
            *(uint4*)&mpt[rr][cc]   = *(const uint4*)(ms);
            *(uint4*)&mpt[rr][cc+8] = *(const uint4*)(ms+8);
        }
        __syncthreads();
        f32x4 acc[4];
        #pragma unroll
        for (int j=0;j<4;j++) acc[j] = (f32x4){0.f,0.f,0.f,0.f};
        #pragma unroll
        for (int ks = 0; ks < 2; ks++){
            #pragma unroll
            for (int nb = 0; nb < 4; nb++){
                bf8 bb = *(const bf8*)&kt[nb*16 + lc][ks*32 + quad*8];
                acc[nb] = MFMA(aq[ks], bb, acc[nb]);
            }
        }
        #pragma unroll
        for (int r = 0; r < 4; r++){
            int row = wv_*16 + quad*4 + r;
            float mm = sm[row], li = sli[row];
            #pragma unroll
            for (int nb = 0; nb < 4; nb++){
                int col = nb*16 + lc;
                float s2v = fmaf(acc[nb][r], C2, b2f(mpt[row][col])) - mm;
                mpt[row][col] = f2b(exp2f(s2v)*li);
            }
        }
        __syncthreads();
        #pragma unroll
        for (int ks = 0; ks < 2; ks++){
            bf8 ap = *(const bf8*)&mpt[wv_*16 + lc][ks*32 + quad*8];
            #pragma unroll
            for (int nb = 0; nb < 4; nb++){
                bf8 bb = *(const bf8*)&vt[nb*16 + lc][ks*32 + quad*8];
                oacc[nb] = MFMA(ap, bb, oacc[nb]);
            }
        }
    }
    #pragma unroll
    for (int r = 0; r < 4; r++){
        int tok = qs0 + wv_*16 + quad*4 + r;
        #pragma unroll
        for (int nb = 0; nb < 4; nb++){
            int hd = nb*16 + lc;
            ctxh[((size_t)(b*Sc + tok))*Ec + h*HDc + hd] = f2b(oacc[nb][r]);
        }
    }
}

// ---------------------------------------------------------------------------
// 9b. sum the two bf16 ctx partials: c0 += c1 (elementwise, bf16)
// ---------------------------------------------------------------------------
__global__ __launch_bounds__(256) void k_addc(u16* __restrict__ c0,
                                              const u16* __restrict__ c1)
{
    int i = (blockIdx.x*256 + threadIdx.x)*8;
    ushort4 a0 = *(ushort4*)&c0[i],   a1 = *(ushort4*)&c0[i+4];
    ushort4 b0 = *(const ushort4*)&c1[i], b1 = *(const ushort4*)&c1[i+4];
    ushort4 o0, o1;
    o0.x = f2b(b2f(a0.x)+b2f(b0.x)); o0.y = f2b(b2f(a0.y)+b2f(b0.y));
    o0.z = f2b(b2f(a0.z)+b2f(b0.z)); o0.w = f2b(b2f(a0.w)+b2f(b0.w));
    o1.x = f2b(b2f(a1.x)+b2f(b1.x)); o1.y = f2b(b2f(a1.y)+b2f(b1.y));
    o1.z = f2b(b2f(a1.z)+b2f(b1.z)); o1.w = f2b(b2f(a1.w)+b2f(b1.w));
    *(ushort4*)&c0[i]   = o0;
    *(ushort4*)&c0[i+4] = o1;
}

// ---------------------------------------------------------------------------
// 10. output projection, MFMA. grid (8, NTILES).
// ---------------------------------------------------------------------------
__global__ __launch_bounds__(256) void k_oproj(
    const u16* __restrict__ ctxb, const u16* __restrict__ woT,
    const int* __restrict__ perm, const int* __restrict__ tmeta,
    float* __restrict__ opre)
{
    int meta = tmeta[blockIdx.y];
    if (meta < 0) return;
    int b = meta >> 1, m = meta & 1;
    const u16* W = woT + (size_t)m*Ec*Dc;
    int c0 = blockIdx.x*128;
    int t = threadIdx.x, lane = t & 63, wv_ = t >> 6;
    int quad = lane >> 4, lc = lane & 15;
    __shared__ u16 at[128][72];
    __shared__ u16 bt[128][72];
    __shared__ int sperm[128];
    if (t < 128) sperm[t] = perm[blockIdx.y*128 + t];
    f32x4 acc[2][8];
    #pragma unroll
    for (int i=0;i<2;i++)
        #pragma unroll
        for (int j=0;j<8;j++) acc[i][j] = (f32x4){0.f,0.f,0.f,0.f};
    __syncthreads();

    int rr = t >> 1, hf = t & 1;
    for (int d0 = 0; d0 < Ec; d0 += 64){
        int s_ = sperm[rr];
        if (s_ >= 0){
            const u16* src = ctxb + ((size_t)(b*Sc + s_))*Ec + d0 + hf*32;
            *(uint4*)&at[rr][hf*32]      = *(const uint4*)(src);
            *(uint4*)&at[rr][hf*32 + 8]  = *(const uint4*)(src + 8);
            *(uint4*)&at[rr][hf*32 + 16] = *(const uint4*)(src + 16);
            *(uint4*)&at[rr][hf*32 + 24] = *(const uint4*)(src + 24);
        } else {
            uint4 z = make_uint4(0,0,0,0);
            *(uint4*)&at[rr][hf*32]      = z;
            *(uint4*)&at[rr][hf*32 + 8]  = z;
            *(uint4*)&at[rr][hf*32 + 16] = z;
            *(uint4*)&at[rr][hf*32 + 24] = z;
        }
        const u16* wsrc = W + (size_t)(c0 + rr)*Ec + d0 + hf*32;
        *(uint4*)&bt[rr][hf*32]      = *(const uint4*)(wsrc);
        *(uint4*)&bt[rr][hf*32 + 8]  = *(const uint4*)(wsrc + 8);
        *(uint4*)&bt[rr][hf*32 + 16] = *(const uint4*)(wsrc + 16);
        *(uint4*)&bt[rr][hf*32 + 24] = *(const uint4*)(wsrc + 24);
        __syncthreads();
        #pragma unroll
        for (int ks = 0; ks < 2; ks++){
            bf8 a0 = *(const bf8*)&at[wv_*32 + lc][ks*32 + quad*8];
            bf8 a1 = *(const bf8*)&at[wv_*32 + 16 + lc][ks*32 + quad*8];
            #pragma unroll
            for (int nb = 0; nb < 8; nb++){
                bf8 bb = *(const bf8*)&bt[nb*16 + lc][ks*32 + quad*8];
                acc[0][nb] = MFMA(a0, bb, acc[0][nb]);
                acc[1][nb] = MFMA(a1, bb, acc[1][nb]);
            }
        }
        __syncthreads();
    }
    #pragma unroll
    for (int mb = 0; mb < 2; mb++){
        #pragma unroll
        for (int r = 0; r < 4; r++){
            int row = wv_*32 + mb*16 + quad*4 + r;
            int s_ = sperm[row];
            if (s_ < 0) continue;
            #pragma unroll
            for (int nb = 0; nb < 8; nb++){
                int col = c0 + nb*16 + lc;
                opre[((size_t)(b*Sc + s_))*Dc + col] = acc[mb][nb][r];
            }
        }
    }
}

// ---------------------------------------------------------------------------
// 11. final RMSNorm over D -> out
// ---------------------------------------------------------------------------
__global__ __launch_bounds__(256) void k_onorm(
    const float* __restrict__ opre, const float* __restrict__ anw,
    const int* __restrict__ mod, float* __restrict__ out)
{
    int row = blockIdx.x;
    int m = mod[row];
    int t = threadIdx.x;
    float val[4];
    float ss = 0.f;
    #pragma unroll
    for (int j=0;j<4;j++){
        val[j] = opre[(size_t)row*Dc + t + 256*j];
        ss += val[j]*val[j];
    }
    #pragma unroll
    for (int o=32;o>0;o>>=1) ss += __shfl_xor(ss, o, 64);
    __shared__ float red[4];
    int wid = t>>6, lane = t&63;
    if (lane==0) red[wid]=ss;
    __syncthreads();
    float tot = red[0]+red[1]+red[2]+red[3];
    float rms = rsqrtf(tot*(1.f/1024.f) + EPSc);
    #pragma unroll
    for (int j=0;j<4;j++)
        out[(size_t)row*Dc + t + 256*j] = val[j]*rms*anw[m*Dc + t + 256*j];
}

// ---------------------------------------------------------------------------
extern "C" void kernel_launch(void* const* d_in, const int* in_sizes, int n_in,
                              void* d_out, int out_size, void* d_ws, size_t ws_size,
                              hipStream_t stream)
{
    const float* x    = (const float*)d_in[0];
    const float* mask = (const float*)d_in[1];
    const int*   mod  = (const int*)  d_in[2];
    const float* Wq   = (const float*)d_in[3];
    const float* Wk   = (const float*)d_in[4];
    const float* Wv   = (const float*)d_in[5];
    const float* Wo   = (const float*)d_in[6];
    const float* qnw  = (const float*)d_in[7];
    const float* knw  = (const float*)d_in[8];
    const float* anw  = (const float*)d_in[9];

    float* out   = (float*)d_out;                 // [B,S,D]
    float* awout = out + (size_t)Bc*Sc*Dc;        // [B,S,S]

    float* ws = (float*)d_ws;
    u16* qb    = (u16*)(ws + 0);
    u16* kb    = (u16*)(ws + 2097152);
    u16* vb    = (u16*)(ws + 4194304);   // dead after k_vt -> ctx partial 1
    u16* xb    = (u16*)(ws + 6291456);   // dead after k_qkv -> ctx partial 0
    u16* ctx0  = xb;
    u16* ctx1  = vb;
    u16* vtb   = (u16*)(ws + 8388608);
    u16* wqT   = (u16*)(ws + 10485760);
    u16* wkT   = (u16*)(ws + 11534336);
    u16* wvT   = (u16*)(ws + 12582912);
    u16* woT   = (u16*)(ws + 13631488);
    float* mst = ws + 14680064;
    float* lst = ws + 14745600;
    float* pmst= ws + 14811136;
    float* plst= ws + 15073280;
    u16* maskb = (u16*)(ws + 15335424);  // mask*log2e, bf16
    int* perm  = (int*)(ws + 17432576);
    int* tmeta = perm + NTILES*TILE_R;
    float* opre = ws;                    // aliases qb+kb (dead by then)

    k_perm  <<<dim3(1),            256, 0, stream>>>(mod, perm, tmeta);
    k_f2b   <<<dim3(4096),         256, 0, stream>>>(x, xb, Bc*Sc*Dc);
    k_f2bs  <<<dim3(4096),         256, 0, stream>>>(mask, maskb, Sc*Sc, LOG2E);
    k_tcvt  <<<dim3(32,32,8),      256, 0, stream>>>(Wq, Wk, Wv, Wo, wqT, wkT, wvT, woT);
    k_qkv   <<<dim3(8,NTILES,3),   256, 0, stream>>>(xb, wqT, wkT, wvT, perm, tmeta,
                                                     qnw, knw, qb, kb, vb);
    k_vt    <<<dim3(32,32),        256, 0, stream>>>(vb, vtb);
    k_stats <<<dim3(16,16,8),      256, 0, stream>>>(qb, kb, maskb, pmst, plst);
    k_merge <<<dim3(256),          256, 0, stream>>>(pmst, plst, mst, lst);
    k_attnw <<<dim3(32,32,2),      256, 0, stream>>>(qb, kb, maskb, mst, lst, awout);
    k_flash <<<dim3(32,16,4),      256, 0, stream>>>(qb, kb, vtb, maskb, mst, lst, ctx0, ctx1);
    k_addc  <<<dim3(2048),         256, 0, stream>>>(ctx0, ctx1);
    k_oproj <<<dim3(8,NTILES),     256, 0, stream>>>(ctx0, woT, perm, tmeta, opre);
    k_onorm <<<dim3(4096),         256, 0, stream>>>(opre, anw, mod, out);
}